// Round 5
// baseline (1392.265 us; speedup 1.0000x reference)
//
#include <hip/hip_runtime.h>
#include <stdint.h>

typedef unsigned short u16;
using half8   = __attribute__((ext_vector_type(8))) _Float16;
using half4v  = __attribute__((ext_vector_type(4))) _Float16;
using half2v  = __attribute__((ext_vector_type(2))) _Float16;
using float4v = __attribute__((ext_vector_type(4))) float;

#define L2E 1.4426950408889634f

__device__ inline float4v f4zero() { float4v z = {0.f, 0.f, 0.f, 0.f}; return z; }

__device__ inline u16 f2h(float f) {
  union { _Float16 h; u16 u; } v; v.h = (_Float16)f; return v.u;
}
__device__ inline float h2f(u16 u) {
  union { u16 u; _Float16 h; } v; v.u = u; return (float)v.h;
}

__device__ inline half2v cvtpk(float a, float b) {
  return __builtin_bit_cast(half2v, __builtin_amdgcn_cvt_pkrtz(a, b));
}
// f16 exp2 via VOP1 v_exp_f16 (self-contained; no OCML/builtin dependency)
__device__ inline _Float16 hexp2_(_Float16 x) {
  _Float16 r;
  asm("v_exp_f16 %0, %1" : "=v"(r) : "v"(x));
  return r;
}
// l += p.x + p.y with f32 accumulate (v_dot2_f32_f16 against (1,1))
__device__ inline float fdot2f(half2v a, float c) {
#if __has_builtin(__builtin_amdgcn_fdot2)
  typedef __attribute__((ext_vector_type(2))) __fp16 h2r;
  return __builtin_amdgcn_fdot2(__builtin_bit_cast(h2r, a),
                                __builtin_bit_cast(h2r, 0x3C003C00u), c, false);
#else
  return c + (float)a.x + (float)a.y;
#endif
}

// async global->LDS, 16B/lane. LDS dest = wave-uniform base + lane*16 (HW).
__device__ inline void glds16(const u16* g, u16* lds_base, int lane) {
#if __has_builtin(__builtin_amdgcn_global_load_lds)
  (void)lane;
  __builtin_amdgcn_global_load_lds((const __attribute__((address_space(1))) void*)g,
                                   (__attribute__((address_space(3))) void*)lds_base,
                                   16, 0, 0);
#else
  *(uint4*)(lds_base + (size_t)lane * 8) = *(const uint4*)g;
#endif
}

// ---------------------------------------------------------------------------
// fp32 (K,N) row-major -> f16 (N,K) row-major, per-layer stride out_ls elems.
// ---------------------------------------------------------------------------
__global__ __launch_bounds__(256) void transpose_cast_kernel(
    const float* __restrict__ in, u16* __restrict__ out, int K, int N, size_t out_ls) {
  __shared__ float tile[32][33];
  const int tx = threadIdx.x & 31, ty = threadIdx.x >> 5;
  in  += (size_t)blockIdx.z * K * N;
  out += (size_t)blockIdx.z * out_ls;
  const int n  = blockIdx.x * 32 + tx;
  const int k0 = blockIdx.y * 32;
#pragma unroll
  for (int j = 0; j < 32; j += 8)
    tile[ty + j][tx] = in[(size_t)(k0 + ty + j) * N + n];
  __syncthreads();
  const int k = k0 + tx;
  const int n0 = blockIdx.x * 32;
#pragma unroll
  for (int j = 0; j < 32; j += 8)
    out[(size_t)(n0 + ty + j) * K + k] = f2h(tile[tx][ty + j]);
}

__global__ __launch_bounds__(256) void cast_kernel(const float* __restrict__ in,
                                                   u16* __restrict__ out) {
  const int i = (blockIdx.x * 256 + threadIdx.x) * 4;
  float4 t = *(const float4*)(in + i);
  ushort4 o;
  o.x = f2h(t.x); o.y = f2h(t.y); o.z = f2h(t.z); o.w = f2h(t.w);
  *(ushort4*)(out + i) = o;
}

// pb fp32 (1,8,2048,2048) -> pbT f16 [8][32][2048][64] perm pos=mm*4+nb, *L2E
__global__ __launch_bounds__(256) void pb_tile_kernel(const float* __restrict__ pb,
                                                      u16* __restrict__ pbT) {
  const int g  = blockIdx.x * 256 + threadIdx.x;
  const int mm = g & 15;
  const int q  = (g >> 4) & 2047;
  const int kbh = g >> 15;
  const int kb = kbh & 31, h = kbh >> 5;
  const float* src = pb + ((size_t)h * 2048 + q) * 2048 + kb * 64 + mm;
  ushort4 o;
  o.x = f2h(src[0]  * L2E);
  o.y = f2h(src[16] * L2E);
  o.z = f2h(src[32] * L2E);
  o.w = f2h(src[48] * L2E);
  *(ushort4*)(pbT + ((size_t)(h * 32 + kb) * 2048 + q) * 64 + mm * 4) = o;
}

// lag scale inv (head- and layer-independent) -> invT f16 [4][32][2048][64],
// perm pos=mm*4+nb, with L2E folded in.  inv = (u+60000)/(9u+480000), u>=0.
__global__ __launch_bounds__(256) void inv_tile_kernel(const int* __restrict__ ts,
                                                       u16* __restrict__ invT) {
  const int g  = blockIdx.x * 256 + threadIdx.x;   // 4*32*2048*16 = 2^22
  const int mm = g & 15;
  const int q  = (g >> 4) & 2047;
  const int kb = (g >> 15) & 31;
  const int b  = g >> 20;
  const int tq = ts[b * 2048 + q];
  ushort4 o;
  u16* op = (u16*)&o;
#pragma unroll
  for (int nb = 0; nb < 4; nb++) {
    const int k = kb * 64 + nb * 16 + mm;
    const int du = tq - ts[b * 2048 + k];
    const float u = (du > 0) ? (float)du : 0.f;
    op[nb] = f2h(fmaf(u, L2E, 86561.70245333781f) *
                 __builtin_amdgcn_rcpf(fmaf(u, 9.f, 480000.f)));
  }
  *(ushort4*)(invT + ((size_t)(b * 32 + kb) * 2048 + q) * 64 + mm * 4) = o;
}

__global__ __launch_bounds__(256) void maskts_kernel(const float* __restrict__ mask,
                                                     const int* __restrict__ ts,
                                                     float* __restrict__ maskE,
                                                     float* __restrict__ tsf) {
  const int i = blockIdx.x * 256 + threadIdx.x;
  maskE[i] = mask[i] * L2E;
  tsf[i]   = (float)ts[i];
}

// ---------------------------------------------------------------------------
// GEMM C[M,N] = A[M,K]*W, W given as Wt (N,K) f16. BMxBN tile, BK=64.
// v2: double-buffered LDS + ONE barrier per k-tile (flash-v7 pattern): the
// staging DMAs for tile t+1 are issued right after the barrier and stay in
// flight across tile t's whole compute phase; they drain at the NEXT
// barrier's vmcnt(0). Removes the fully-exposed per-iteration DMA latency
// of the old stage->sync->compute->sync loop (K=512 has only 8 iters to
// amortize, so the exposure dominated).
// EPI: 2 = fp32 out = acc+bias+f16 resid; 3 = gelu(acc+bias) f16;
//      4 = fused QKV scatter (Q,K -> (B,NH,S,DH); V -> (B,NH,DH,S) with
//          columns permuted within each 64-token tile: c' = (c&15)*4 | c>>4,
//          matching flash4's P storage order)
// ---------------------------------------------------------------------------
template <int BM, int BN, int NN, int KK, int EPI>
__global__ __launch_bounds__(256) void gemm_kernel(
    const u16* __restrict__ A, const u16* __restrict__ Wt,
    const float* __restrict__ b0, const float* __restrict__ b1, const float* __restrict__ b2,
    const u16* __restrict__ resid,
    void* __restrict__ o0, void* __restrict__ o1, void* __restrict__ o2) {
  constexpr int FI = BM / 32;
  constexpr int FJB = BN / 32;
  constexpr int FIW = BM / 32;
  constexpr int FJW = BN / 32;
  constexpr int NT = KK / 64;
  __shared__ __align__(16) u16 As[2][BM * 64];
  __shared__ __align__(16) u16 Bs[2][BN * 64];
  const int tid = threadIdx.x, lane = tid & 63, wv = tid >> 6;
  const int quad = lane >> 4, mm = lane & 15;
  const int m0 = blockIdx.x * BM, n0 = blockIdx.y * BN;
  const int wm = (wv >> 1) * (BM / 2), wn = (wv & 1) * (BN / 2);
  const int srow = tid >> 3, slot = tid & 7;
  const int chunk = slot ^ (srow & 7);
  const u16* Ag = A  + (size_t)(m0 + srow) * KK + chunk * 8;
  const u16* Bg = Wt + (size_t)(n0 + srow) * KK + chunk * 8;
  const int sw = mm & 7;

  float4v acc[FIW][FJW];
#pragma unroll
  for (int i = 0; i < FIW; i++)
#pragma unroll
    for (int j = 0; j < FJW; j++) acc[i][j] = f4zero();

  // prologue: stage k-tile 0 into buffer 0
#pragma unroll
  for (int i = 0; i < FI; i++)
    glds16(Ag + (size_t)i * 32 * KK, &As[0][(size_t)(wv * 8 + i * 32) * 64], lane);
#pragma unroll
  for (int j = 0; j < FJB; j++)
    glds16(Bg + (size_t)j * 32 * KK, &Bs[0][(size_t)(wv * 8 + j * 32) * 64], lane);

  int cur = 0;
#pragma unroll 2
  for (int kt = 0; kt < NT; kt++) {
    __syncthreads();   // buf[cur] staged & drained; prior readers of buf[cur^1] done

    // issue next tile's staging immediately -> overlaps this tile's compute
    if (kt + 1 < NT) {
      const size_t ko = (size_t)(kt + 1) * 64;
#pragma unroll
      for (int i = 0; i < FI; i++)
        glds16(Ag + (size_t)i * 32 * KK + ko, &As[cur ^ 1][(size_t)(wv * 8 + i * 32) * 64], lane);
#pragma unroll
      for (int j = 0; j < FJB; j++)
        glds16(Bg + (size_t)j * 32 * KK + ko, &Bs[cur ^ 1][(size_t)(wv * 8 + j * 32) * 64], lane);
    }

#pragma unroll
    for (int ks = 0; ks < 2; ks++) {
      half8 a[FIW], b[FJW];
#pragma unroll
      for (int i = 0; i < FIW; i++)
        a[i] = *(const half8*)(&As[cur][0] + (size_t)(wm + i * 16 + mm) * 64 + (size_t)((ks * 4 + quad) ^ sw) * 8);
#pragma unroll
      for (int j = 0; j < FJW; j++)
        b[j] = *(const half8*)(&Bs[cur][0] + (size_t)(wn + j * 16 + mm) * 64 + (size_t)((ks * 4 + quad) ^ sw) * 8);
#pragma unroll
      for (int i = 0; i < FIW; i++)
#pragma unroll
        for (int j = 0; j < FJW; j++)
          acc[i][j] = __builtin_amdgcn_mfma_f32_16x16x32_f16(a[i], b[j], acc[i][j], 0, 0, 0);
    }
    cur ^= 1;
  }

#pragma unroll
  for (int j = 0; j < FJW; j++) {
    const int gn = n0 + wn + j * 16 + mm;
    if (EPI == 4) {
      const int which = gn >> 9, col = gn & 511, h = (gn >> 6) & 7, d = gn & 63;
      const float* bp = (which == 0) ? b0 : (which == 1) ? b1 : b2;
      const float bias = bp[col];
      u16* dst = (which == 0) ? (u16*)o0 : (which == 1) ? (u16*)o1 : (u16*)o2;
#pragma unroll
      for (int i = 0; i < FIW; i++)
#pragma unroll
        for (int r = 0; r < 4; r++) {
          const int gm = m0 + wm + i * 16 + quad * 4 + r;
          const int b_ = gm >> 11, s_ = gm & 2047;
          const float val = acc[i][j][r] + bias;
          if (which < 2)
            dst[((size_t)((b_ * 8 + h) * 2048 + s_)) * 64 + d] = f2h(val);
          else
            dst[((size_t)((b_ * 8 + h) * 64 + d)) * 2048 +
                (s_ & ~63) + (((s_ & 15) << 2) | ((s_ >> 4) & 3))] = f2h(val);
        }
    } else {
      const float bias = b0[gn];
#pragma unroll
      for (int i = 0; i < FIW; i++)
#pragma unroll
        for (int r = 0; r < 4; r++) {
          const int gm = m0 + wm + i * 16 + quad * 4 + r;
          const float val = acc[i][j][r] + bias;
          const size_t idx = (size_t)gm * NN + gn;
          if (EPI == 2) {
            ((float*)o0)[idx] = val + h2f(resid[idx]);
          } else {  // EPI == 3: exact-erf GELU -> f16
            const float z  = val * 0.70710678118654752f;
            const float az = fabsf(z);
            const float t  = __builtin_amdgcn_rcpf(1.0f + 0.3275911f * az);
            const float poly = t * (0.254829592f + t * (-0.284496736f +
                               t * (1.421413741f + t * (-1.453152027f + t * 1.061405429f))));
            const float e = __builtin_amdgcn_exp2f(-az * az * L2E);
            float erf_ = 1.0f - poly * e;
            erf_ = (z < 0.0f) ? -erf_ : erf_;
            ((u16*)o0)[idx] = f2h(val * 0.5f * (1.0f + erf_));
          }
        }
    }
  }
}

// ---------------------------------------------------------------------------
// Flash v8 (f16): 8 waves / 512 threads, 128 q-rows per block, grid (16,32).
// v7 + #pragma unroll 2 on the k-tile loop: 'cur' becomes compile-time
// (no LDS-pointer selects) and the software-pipeline rotate (pbc=pbn etc,
// ~40 v_mov/iter) becomes pure register renaming.
// Issue order per iter: (1) softmax-operand prefetches FIRST (oldest in
// vmcnt FIFO), (2) staging DMAs second -> end-of-iter waits resolve early,
// staging stays in flight until next barrier's vmcnt(0) drain.
// s_setprio(1) wraps both MFMA clusters (T5).
// Packed-f16 softmax; P stored permuted-k (k' = (k&15)*4 | k>>4), b64 writes,
// XOR-swizzled rows -> zero bank conflicts (verified round 2).
// TILED: 2 = pbT+invT, 1 = pbT only (inv on the fly), 0 = raw pb32.
// ---------------------------------------------------------------------------
template <int TILED>
__global__ __launch_bounds__(512) void flash4_kernel(
    const u16* __restrict__ Q, const u16* __restrict__ Kb, const u16* __restrict__ Vt,
    const u16* __restrict__ pbT, const u16* __restrict__ invT,
    const float* __restrict__ pb32,
    const float* __restrict__ maskE, const float* __restrict__ tsf,
    u16* __restrict__ ctx) {
  __shared__ __align__(16) u16 Kls[2][64 * 64];
  __shared__ __align__(16) u16 Vls[2][64 * 64];
  __shared__ __align__(16) u16 P[8][16 * 64];
  const int tid = threadIdx.x, lane = tid & 63, w = tid >> 6;   // w in [0,8)
  const int quad = lane >> 4, mm = lane & 15;
  const int bh = blockIdx.y, b_ = bh >> 3, h_ = bh & 7;
  const int q0 = blockIdx.x * 128 + w * 16;
  const size_t qk_base = (size_t)bh * 2048 * 64;
  const size_t v_base  = (size_t)bh * 64 * 2048;
  const int srow = lane >> 3, slot = lane & 7;
  const int chunk = slot ^ srow;
  const int sw = mm & 7;

  // staging: each wave stages 8 rows (w*8 + srow) of K and V per tile.
  const u16* Kgl = Kb + qk_base + (size_t)(w * 8 + srow) * 64 + chunk * 8;
  const u16* Vgl = Vt + v_base + (size_t)(w * 8 + srow) * 2048 + chunk * 8;

  // stage k-tile 0 into buffer 0 (issued before everything else)
  glds16(Kgl, &Kls[0][(w * 8) * 64], lane);
  glds16(Vgl, &Vls[0][(w * 8) * 64], lane);

  half8 aq[2];
#pragma unroll
  for (int t = 0; t < 2; t++)
    aq[t] = *(const half8*)(Q + qk_base + (size_t)(q0 + mm) * 64 + t * 32 + quad * 8);

  float tqf[4];
  if (TILED < 2) {
#pragma unroll
    for (int r = 0; r < 4; r++) tqf[r] = tsf[b_ * 2048 + q0 + quad * 4 + r];
  }

  float l_r[4] = {0.f, 0.f, 0.f, 0.f};
  float4v o[4];
#pragma unroll
  for (int ob = 0; ob < 4; ob++) o[ob] = f4zero();

  // prefetch tile-0 per-lane softmax operands
  ushort4 pbc[4], invc[4]; float tkc[4], mkc[4];
  if (TILED >= 1) {
#pragma unroll
    for (int r = 0; r < 4; r++)
      pbc[r] = *(const ushort4*)(pbT + ((size_t)(h_ * 32) * 2048 + q0 + quad * 4 + r) * 64 + mm * 4);
  }
  if (TILED == 2) {
#pragma unroll
    for (int r = 0; r < 4; r++)
      invc[r] = *(const ushort4*)(invT + ((size_t)(b_ * 32) * 2048 + q0 + quad * 4 + r) * 64 + mm * 4);
  } else {
#pragma unroll
    for (int nb = 0; nb < 4; nb++) tkc[nb] = tsf[b_ * 2048 + nb * 16 + mm];
  }
#pragma unroll
  for (int nb = 0; nb < 4; nb++) mkc[nb] = maskE[b_ * 2048 + nb * 16 + mm];

  int cur = 0;
#pragma unroll 2
  for (int kt = 0; kt < 32; kt++) {
    const int k0 = kt * 64;
    __syncthreads();   // drains prev iter's staging; buf[cur] ready for all waves

    // (1) softmax-operand prefetch for next tile — issued FIRST (oldest in
    //     vmcnt FIFO) so waiting on these leaves the staging DMAs in flight.
    const int kn = (kt < 31) ? kt + 1 : kt;
    ushort4 pbn[4], invn[4]; float tkn[4], mkn[4];
    if (TILED >= 1) {
#pragma unroll
      for (int r = 0; r < 4; r++)
        pbn[r] = *(const ushort4*)(pbT + ((size_t)(h_ * 32 + kn) * 2048 + q0 + quad * 4 + r) * 64 + mm * 4);
    }
    if (TILED == 2) {
#pragma unroll
      for (int r = 0; r < 4; r++)
        invn[r] = *(const ushort4*)(invT + ((size_t)(b_ * 32 + kn) * 2048 + q0 + quad * 4 + r) * 64 + mm * 4);
    } else {
#pragma unroll
      for (int nb = 0; nb < 4; nb++) tkn[nb] = tsf[b_ * 2048 + kn * 64 + nb * 16 + mm];
    }
#pragma unroll
    for (int nb = 0; nb < 4; nb++) mkn[nb] = maskE[b_ * 2048 + kn * 64 + nb * 16 + mm];

    // (2) stage next K/V tile — these 2 DMAs stay in flight until the next
    //     barrier's vmcnt(0) drain, overlapping this tile's full compute.
    if (kt < 31) {
      const size_t ko = (size_t)(kt + 1) * 4096;
      const size_t vo = (size_t)(kt + 1) * 64;
      glds16(Kgl + ko, &Kls[cur ^ 1][(w * 8) * 64], lane);
      glds16(Vgl + vo, &Vls[cur ^ 1][(w * 8) * 64], lane);
    }

    // (3) QK^T from LDS
    const u16* Kc = Kls[cur];
    float4v s[4];
    __builtin_amdgcn_s_setprio(1);
#pragma unroll
    for (int nb = 0; nb < 4; nb++) {
      const half8 kf0 = *(const half8*)(Kc + (size_t)(nb * 16 + mm) * 64 + (size_t)(quad ^ sw) * 8);
      const half8 kf1 = *(const half8*)(Kc + (size_t)(nb * 16 + mm) * 64 + (size_t)((4 + quad) ^ sw) * 8);
      s[nb] = __builtin_amdgcn_mfma_f32_16x16x32_f16(aq[0], kf0, f4zero(), 0, 0, 0);
      s[nb] = __builtin_amdgcn_mfma_f32_16x16x32_f16(aq[1], kf1, s[nb], 0, 0, 0);
    }
    __builtin_amdgcn_s_setprio(0);

    // (4) packed-f16 softmax + P write (b64, XOR-swizzled, permuted-k layout)
    const half2v mk01 = cvtpk(mkc[0], mkc[1]);
    const half2v mk23 = cvtpk(mkc[2], mkc[3]);
#pragma unroll
    for (int r = 0; r < 4; r++) {
      half2v pb01, pb23, iv01, iv23;
      if (TILED >= 1) {
        pb01 = *(const half2v*)&pbc[r].x;
        pb23 = *(const half2v*)&pbc[r].z;
      } else {
        float pv[4];
#pragma unroll
        for (int nb = 0; nb < 4; nb++)
          pv[nb] = pb32[((size_t)h_ * 2048 + q0 + quad * 4 + r) * 2048 + k0 + nb * 16 + mm] * L2E;
        pb01 = cvtpk(pv[0], pv[1]); pb23 = cvtpk(pv[2], pv[3]);
      }
      if (TILED == 2) {
        iv01 = *(const half2v*)&invc[r].x;
        iv23 = *(const half2v*)&invc[r].z;
      } else {
        float ivv[4];
#pragma unroll
        for (int nb = 0; nb < 4; nb++) {
          const float u = fmaxf(tqf[r] - tkc[nb], 0.f);
          ivv[nb] = fmaf(u, L2E, 86561.70245333781f) *
                    __builtin_amdgcn_rcpf(fmaf(u, 9.f, 480000.f));
        }
        iv01 = cvtpk(ivv[0], ivv[1]); iv23 = cvtpk(ivv[2], ivv[3]);
      }
      const half2v s01 = cvtpk(s[0][r], s[1][r]);
      const half2v s23 = cvtpk(s[2][r], s[3][r]);
      const half2v t01 = __builtin_elementwise_fma(s01, iv01, pb01 + mk01);
      const half2v t23 = __builtin_elementwise_fma(s23, iv23, pb23 + mk23);
      half2v p01, p23;
      p01.x = hexp2_(t01.x); p01.y = hexp2_(t01.y);
      p23.x = hexp2_(t23.x); p23.y = hexp2_(t23.y);
      l_r[r] = fdot2f(p01, l_r[r]);
      l_r[r] = fdot2f(p23, l_r[r]);
      const int prow = quad * 4 + r;
      union { half2v h2[2]; half4v h4; } uu;
      uu.h2[0] = p01; uu.h2[1] = p23;
      *(half4v*)((char*)P[w] + prow * 128 + ((mm * 8) ^ ((prow & 7) << 4))) = uu.h4;
    }

    // (5) PV from LDS (A = P in permuted-k storage, B = V with matching k order)
    const u16* Vc = Vls[cur];
    const char* Pb = (const char*)P[w] + mm * 128;
    const int pxor = (mm & 7) << 4;
    const half8 ap0 = *(const half8*)(Pb + ((quad * 16) ^ pxor));
    const half8 ap1 = *(const half8*)(Pb + ((64 + quad * 16) ^ pxor));
    __builtin_amdgcn_s_setprio(1);
#pragma unroll
    for (int ob = 0; ob < 4; ob++) {
      const half8 vf0 = *(const half8*)(Vc + (size_t)(ob * 16 + mm) * 64 + (size_t)(quad ^ sw) * 8);
      const half8 vf1 = *(const half8*)(Vc + (size_t)(ob * 16 + mm) * 64 + (size_t)((4 + quad) ^ sw) * 8);
      o[ob] = __builtin_amdgcn_mfma_f32_16x16x32_f16(ap0, vf0, o[ob], 0, 0, 0);
      o[ob] = __builtin_amdgcn_mfma_f32_16x16x32_f16(ap1, vf1, o[ob], 0, 0, 0);
    }
    __builtin_amdgcn_s_setprio(0);

    // (6) rotate prefetched operands (renamed away by unroll-2)
#pragma unroll
    for (int r = 0; r < 4; r++) { pbc[r] = pbn[r]; invc[r] = invn[r]; }
#pragma unroll
    for (int nb = 0; nb < 4; nb++) { tkc[nb] = tkn[nb]; mkc[nb] = mkn[nb]; }
    cur ^= 1;
  }

#pragma unroll
  for (int r = 0; r < 4; r++) {
    float l = l_r[r];
#pragma unroll
    for (int sh = 1; sh < 16; sh <<= 1) l += __shfl_xor(l, sh, 64);  // sum over mm within quad-group
    const float rl = __builtin_amdgcn_rcpf(l);
    const int qrow = q0 + quad * 4 + r;
#pragma unroll
    for (int ob = 0; ob < 4; ob++)
      ctx[((size_t)b_ * 2048 + qrow) * 512 + h_ * 64 + ob * 16 + mm] = f2h(o[ob][r] * rl);
  }
}

// ---------------------------------------------------------------------------
// LayerNorm over H=512: 1 wave/row, 4 rows/block. f16 out always, f32 optional.
// ---------------------------------------------------------------------------
__global__ __launch_bounds__(256) void ln_kernel(
    const float* __restrict__ in, const float* __restrict__ g, const float* __restrict__ bb,
    float* __restrict__ of, u16* __restrict__ obf) {
  const int lane = threadIdx.x & 63, w = threadIdx.x >> 6;
  const int row = blockIdx.x * 4 + w;
  const float* x = in + (size_t)row * 512;
  float v[8];
  const float4 t0 = *(const float4*)(x + lane * 8);
  const float4 t1 = *(const float4*)(x + lane * 8 + 4);
  v[0] = t0.x; v[1] = t0.y; v[2] = t0.z; v[3] = t0.w;
  v[4] = t1.x; v[5] = t1.y; v[6] = t1.z; v[7] = t1.w;
  float s = 0.f;
#pragma unroll
  for (int i = 0; i < 8; i++) s += v[i];
#pragma unroll
  for (int sh = 1; sh < 64; sh <<= 1) s += __shfl_xor(s, sh, 64);
  const float mean = s * (1.0f / 512.0f);
  float sq = 0.f;
#pragma unroll
  for (int i = 0; i < 8; i++) { const float d = v[i] - mean; sq += d * d; }
#pragma unroll
  for (int sh = 1; sh < 64; sh <<= 1) sq += __shfl_xor(sq, sh, 64);
  const float rstd = rsqrtf(sq * (1.0f / 512.0f) + 1e-12f);
#pragma unroll
  for (int i = 0; i < 8; i++) {
    const int col = lane * 8 + i;
    const float y = (v[i] - mean) * rstd * g[col] + bb[col];
    if (of) of[(size_t)row * 512 + col] = y;
    obf[(size_t)row * 512 + col] = f2h(y);
  }
}

// ---------------------------------------------------------------------------
extern "C" void kernel_launch(void* const* d_in, const int* in_sizes, int n_in,
                              void* d_out, int out_size, void* d_ws, size_t ws_size,
                              hipStream_t stream) {
  const float* x_in = (const float*)d_in[0];
  const float* mask = (const float*)d_in[1];
  const float* pb   = (const float*)d_in[2];
  const int*   ts   = (const int*)d_in[3];
  const float* wq = (const float*)d_in[4];  const float* bq = (const float*)d_in[5];
  const float* wk = (const float*)d_in[6];  const float* bk = (const float*)d_in[7];
  const float* wvp = (const float*)d_in[8]; const float* bv = (const float*)d_in[9];
  const float* wo = (const float*)d_in[10]; const float* bo = (const float*)d_in[11];
  const float* ln1g = (const float*)d_in[12]; const float* ln1b = (const float*)d_in[13];
  const float* wi = (const float*)d_in[14]; const float* bi = (const float*)d_in[15];
  const float* wo2 = (const float*)d_in[16]; const float* bo2 = (const float*)d_in[17];
  const float* ln2g = (const float*)d_in[18]; const float* ln2b = (const float*)d_in[19];

  char* ws = (char*)d_ws;
  const size_t o_wqkv  = 0;
  const size_t o_woT   = 6291456;
  const size_t o_wiT   = 8388608;
  const size_t o_wo2T  = 16777216;
  const size_t o_maskE = 25165824;
  const size_t o_tsf   = 25198592;
  const size_t o_xbf   = 25231360;
  const size_t o_qb    = 33619968;
  const size_t o_kb    = 42008576;
  const size_t o_vb    = 50397184;
  const size_t o_ctx   = 58785792;
  const size_t o_attnb = 67174400;
  const size_t o_tmp   = 75563008;
  const size_t o_pbT   = 92340224;    // 67,108,864 B
  const size_t o_invT  = 159449088;   // 33,554,432 B
  const int tiled = (ws_size >= o_invT + 33554432ull) ? 2
                  : (ws_size >= o_pbT + 67108864ull) ? 1 : 0;

  u16*   wqkvT = (u16*)(ws + o_wqkv);
  u16*   woT   = (u16*)(ws + o_woT);
  u16*   wiT   = (u16*)(ws + o_wiT);
  u16*   wo2T  = (u16*)(ws + o_wo2T);
  float* maskE = (float*)(ws + o_maskE);
  float* tsf   = (float*)(ws + o_tsf);
  u16*   xbf   = (u16*)(ws + o_xbf);
  u16*   qb    = (u16*)(ws + o_qb);
  u16*   kb    = (u16*)(ws + o_kb);
  u16*   vb    = (u16*)(ws + o_vb);
  u16*   ctx   = (u16*)(ws + o_ctx);
  u16*   hb    = (u16*)(ws + o_qb);
  u16*   attnb = (u16*)(ws + o_attnb);
  float* tmp   = (float*)(ws + o_tmp);
  u16*   pbT   = (u16*)(ws + o_pbT);
  u16*   invT  = (u16*)(ws + o_invT);

  const dim3 blk(256);
  const dim3 blk512(512);
  transpose_cast_kernel<<<dim3(16, 16, 4), blk, 0, stream>>>(wq,  wqkvT,          512, 512, 786432);
  transpose_cast_kernel<<<dim3(16, 16, 4), blk, 0, stream>>>(wk,  wqkvT + 262144, 512, 512, 786432);
  transpose_cast_kernel<<<dim3(16, 16, 4), blk, 0, stream>>>(wvp, wqkvT + 524288, 512, 512, 786432);
  transpose_cast_kernel<<<dim3(16, 16, 4), blk, 0, stream>>>(wo,  woT,  512, 512,  262144);
  transpose_cast_kernel<<<dim3(64, 16, 4), blk, 0, stream>>>(wi,  wiT,  512, 2048, 1048576);
  transpose_cast_kernel<<<dim3(16, 64, 4), blk, 0, stream>>>(wo2, wo2T, 2048, 512, 1048576);
  maskts_kernel<<<32, blk, 0, stream>>>(mask, ts, maskE, tsf);
  cast_kernel<<<4096, blk, 0, stream>>>(x_in, xbf);
  if (tiled >= 1) pb_tile_kernel<<<32768, blk, 0, stream>>>(pb, pbT);
  if (tiled == 2) inv_tile_kernel<<<16384, blk, 0, stream>>>(ts, invT);

  for (int l = 0; l < 4; l++) {
    gemm_kernel<128, 128, 1536, 512, 4><<<dim3(64, 12), blk, 0, stream>>>(
        xbf, wqkvT + (size_t)l * 786432, bq + l * 512, bk + l * 512, bv + l * 512,
        nullptr, qb, kb, vb);
    if (tiled == 2)
      flash4_kernel<2><<<dim3(16, 32), blk512, 0, stream>>>(qb, kb, vb, pbT, invT, pb, maskE, tsf, ctx);
    else if (tiled == 1)
      flash4_kernel<1><<<dim3(16, 32), blk512, 0, stream>>>(qb, kb, vb, pbT, nullptr, pb, maskE, tsf, ctx);
    else
      flash4_kernel<0><<<dim3(16, 32), blk512, 0, stream>>>(qb, kb, vb, nullptr, nullptr, pb, maskE, tsf, ctx);
    gemm_kernel<128, 64, 512, 512, 2><<<dim3(64, 8), blk, 0, stream>>>(
        ctx, woT + (size_t)l * 262144, bo + l * 512, nullptr, nullptr, xbf,
        tmp, nullptr, nullptr);
    ln_kernel<<<2048, blk, 0, stream>>>(tmp, ln1g + l * 512, ln1b + l * 512, nullptr, attnb);
    gemm_kernel<128, 128, 2048, 512, 3><<<dim3(64, 16), blk, 0, stream>>>(
        attnb, wiT + (size_t)l * 1048576, bi + l * 2048, nullptr, nullptr, nullptr,
        hb, nullptr, nullptr);
    gemm_kernel<128, 64, 512, 2048, 2><<<dim3(64, 8), blk, 0, stream>>>(
        hb, wo2T + (size_t)l * 1048576, bo2 + l * 512, nullptr, nullptr, attnb,
        tmp, nullptr, nullptr);
    ln_kernel<<<2048, blk, 0, stream>>>(tmp, ln2g + l * 512, ln2b + l * 512,
                                        (l == 3) ? (float*)d_out : nullptr, xbf);
  }
  (void)in_sizes; (void)n_in; (void)out_size;
}

// Round 6
// 1158.834 us; speedup vs baseline: 1.2014x; 1.2014x over previous
//
#include <hip/hip_runtime.h>
#include <stdint.h>

typedef unsigned short u16;
using half8   = __attribute__((ext_vector_type(8))) _Float16;
using half4v  = __attribute__((ext_vector_type(4))) _Float16;
using half2v  = __attribute__((ext_vector_type(2))) _Float16;
using float4v = __attribute__((ext_vector_type(4))) float;

#define L2E 1.4426950408889634f

__device__ inline float4v f4zero() { float4v z = {0.f, 0.f, 0.f, 0.f}; return z; }

__device__ inline u16 f2h(float f) {
  union { _Float16 h; u16 u; } v; v.h = (_Float16)f; return v.u;
}
__device__ inline float h2f(u16 u) {
  union { u16 u; _Float16 h; } v; v.u = u; return (float)v.h;
}

__device__ inline half2v cvtpk(float a, float b) {
  return __builtin_bit_cast(half2v, __builtin_amdgcn_cvt_pkrtz(a, b));
}
// f16 exp2 via VOP1 v_exp_f16 (self-contained; no OCML/builtin dependency)
__device__ inline _Float16 hexp2_(_Float16 x) {
  _Float16 r;
  asm("v_exp_f16 %0, %1" : "=v"(r) : "v"(x));
  return r;
}
// l += p.x + p.y with f32 accumulate (v_dot2_f32_f16 against (1,1))
__device__ inline float fdot2f(half2v a, float c) {
#if __has_builtin(__builtin_amdgcn_fdot2)
  typedef __attribute__((ext_vector_type(2))) __fp16 h2r;
  return __builtin_amdgcn_fdot2(__builtin_bit_cast(h2r, a),
                                __builtin_bit_cast(h2r, 0x3C003C00u), c, false);
#else
  return c + (float)a.x + (float)a.y;
#endif
}

// async global->LDS, 16B/lane. LDS dest = wave-uniform base + lane*16 (HW).
__device__ inline void glds16(const u16* g, u16* lds_base, int lane) {
#if __has_builtin(__builtin_amdgcn_global_load_lds)
  (void)lane;
  __builtin_amdgcn_global_load_lds((const __attribute__((address_space(1))) void*)g,
                                   (__attribute__((address_space(3))) void*)lds_base,
                                   16, 0, 0);
#else
  *(uint4*)(lds_base + (size_t)lane * 8) = *(const uint4*)g;
#endif
}

// ---------------------------------------------------------------------------
// fp32 (K,N) row-major -> f16 (N,K) row-major, per-layer stride out_ls elems.
// ---------------------------------------------------------------------------
__global__ __launch_bounds__(256) void transpose_cast_kernel(
    const float* __restrict__ in, u16* __restrict__ out, int K, int N, size_t out_ls) {
  __shared__ float tile[32][33];
  const int tx = threadIdx.x & 31, ty = threadIdx.x >> 5;
  in  += (size_t)blockIdx.z * K * N;
  out += (size_t)blockIdx.z * out_ls;
  const int n  = blockIdx.x * 32 + tx;
  const int k0 = blockIdx.y * 32;
#pragma unroll
  for (int j = 0; j < 32; j += 8)
    tile[ty + j][tx] = in[(size_t)(k0 + ty + j) * N + n];
  __syncthreads();
  const int k = k0 + tx;
  const int n0 = blockIdx.x * 32;
#pragma unroll
  for (int j = 0; j < 32; j += 8)
    out[(size_t)(n0 + ty + j) * K + k] = f2h(tile[tx][ty + j]);
}

__global__ __launch_bounds__(256) void cast_kernel(const float* __restrict__ in,
                                                   u16* __restrict__ out) {
  const int i = (blockIdx.x * 256 + threadIdx.x) * 4;
  float4 t = *(const float4*)(in + i);
  ushort4 o;
  o.x = f2h(t.x); o.y = f2h(t.y); o.z = f2h(t.z); o.w = f2h(t.w);
  *(ushort4*)(out + i) = o;
}

// pb fp32 (1,8,2048,2048) -> pbT f16 [8][32][2048][64] perm pos=mm*4+nb, *L2E
__global__ __launch_bounds__(256) void pb_tile_kernel(const float* __restrict__ pb,
                                                      u16* __restrict__ pbT) {
  const int g  = blockIdx.x * 256 + threadIdx.x;
  const int mm = g & 15;
  const int q  = (g >> 4) & 2047;
  const int kbh = g >> 15;
  const int kb = kbh & 31, h = kbh >> 5;
  const float* src = pb + ((size_t)h * 2048 + q) * 2048 + kb * 64 + mm;
  ushort4 o;
  o.x = f2h(src[0]  * L2E);
  o.y = f2h(src[16] * L2E);
  o.z = f2h(src[32] * L2E);
  o.w = f2h(src[48] * L2E);
  *(ushort4*)(pbT + ((size_t)(h * 32 + kb) * 2048 + q) * 64 + mm * 4) = o;
}

// lag scale inv (head- and layer-independent) -> invT f16 [4][32][2048][64],
// perm pos=mm*4+nb, with L2E folded in.  inv = (u+60000)/(9u+480000), u>=0.
__global__ __launch_bounds__(256) void inv_tile_kernel(const int* __restrict__ ts,
                                                       u16* __restrict__ invT) {
  const int g  = blockIdx.x * 256 + threadIdx.x;   // 4*32*2048*16 = 2^22
  const int mm = g & 15;
  const int q  = (g >> 4) & 2047;
  const int kb = (g >> 15) & 31;
  const int b  = g >> 20;
  const int tq = ts[b * 2048 + q];
  ushort4 o;
  u16* op = (u16*)&o;
#pragma unroll
  for (int nb = 0; nb < 4; nb++) {
    const int k = kb * 64 + nb * 16 + mm;
    const int du = tq - ts[b * 2048 + k];
    const float u = (du > 0) ? (float)du : 0.f;
    op[nb] = f2h(fmaf(u, L2E, 86561.70245333781f) *
                 __builtin_amdgcn_rcpf(fmaf(u, 9.f, 480000.f)));
  }
  *(ushort4*)(invT + ((size_t)(b * 32 + kb) * 2048 + q) * 64 + mm * 4) = o;
}

__global__ __launch_bounds__(256) void maskts_kernel(const float* __restrict__ mask,
                                                     const int* __restrict__ ts,
                                                     float* __restrict__ maskE,
                                                     float* __restrict__ tsf) {
  const int i = blockIdx.x * 256 + threadIdx.x;
  maskE[i] = mask[i] * L2E;
  tsf[i]   = (float)ts[i];
}

// ---------------------------------------------------------------------------
// GEMM C[M,N] = A[M,K]*W, W given as Wt (N,K) f16. BMxBN tile, BK=64.
// Double-buffered LDS + one barrier per k-tile (neutral vs single-buffer,
// kept). EPI: 2 = fp32 out = acc+bias+f16 resid; 3 = gelu(acc+bias) f16;
//      4 = fused QKV scatter (Q,K -> (B,NH,S,DH); V -> (B,NH,DH,S) with
//          columns permuted within each 64-token tile: c' = (c&15)*4 | c>>4).
// V-blocks (n0>=1024, all-V since BN=128) route through an LDS transpose:
// acc+bias -> T[128][130] f16, then 8x coalesced 16B stores per thread along
// s (inverse permutation applied on the LDS read). Replaces 64 scattered 2B
// stores/thread (~64 L2-line touches per store instr) with 8 coalesced ones.
// ---------------------------------------------------------------------------
template <int BM, int BN, int NN, int KK, int EPI>
__global__ __launch_bounds__(256) void gemm_kernel(
    const u16* __restrict__ A, const u16* __restrict__ Wt,
    const float* __restrict__ b0, const float* __restrict__ b1, const float* __restrict__ b2,
    const u16* __restrict__ resid,
    void* __restrict__ o0, void* __restrict__ o1, void* __restrict__ o2) {
  constexpr int FI = BM / 32;
  constexpr int FJB = BN / 32;
  constexpr int FIW = BM / 32;
  constexpr int FJW = BN / 32;
  constexpr int NT = KK / 64;
  __shared__ __align__(16) u16 smem[2 * BM * 64 + 2 * BN * 64];
  u16* As0 = smem;                 // [2][BM*64]
  u16* Bs0 = smem + 2 * BM * 64;   // [2][BN*64]
  const int tid = threadIdx.x, lane = tid & 63, wv = tid >> 6;
  const int quad = lane >> 4, mm = lane & 15;
  const int m0 = blockIdx.x * BM, n0 = blockIdx.y * BN;
  const int wm = (wv >> 1) * (BM / 2), wn = (wv & 1) * (BN / 2);
  const int srow = tid >> 3, slot = tid & 7;
  const int chunk = slot ^ (srow & 7);
  const u16* Ag = A  + (size_t)(m0 + srow) * KK + chunk * 8;
  const u16* Bg = Wt + (size_t)(n0 + srow) * KK + chunk * 8;
  const int sw = mm & 7;

  float4v acc[FIW][FJW];
#pragma unroll
  for (int i = 0; i < FIW; i++)
#pragma unroll
    for (int j = 0; j < FJW; j++) acc[i][j] = f4zero();

  // prologue: stage k-tile 0 into buffer 0
#pragma unroll
  for (int i = 0; i < FI; i++)
    glds16(Ag + (size_t)i * 32 * KK, As0 + (size_t)(wv * 8 + i * 32) * 64, lane);
#pragma unroll
  for (int j = 0; j < FJB; j++)
    glds16(Bg + (size_t)j * 32 * KK, Bs0 + (size_t)(wv * 8 + j * 32) * 64, lane);

  int cur = 0;
#pragma unroll 2
  for (int kt = 0; kt < NT; kt++) {
    __syncthreads();   // buf[cur] staged & drained; prior readers of buf[cur^1] done

    // issue next tile's staging immediately -> overlaps this tile's compute
    if (kt + 1 < NT) {
      const size_t ko = (size_t)(kt + 1) * 64;
#pragma unroll
      for (int i = 0; i < FI; i++)
        glds16(Ag + (size_t)i * 32 * KK + ko,
               As0 + (size_t)(cur ^ 1) * BM * 64 + (size_t)(wv * 8 + i * 32) * 64, lane);
#pragma unroll
      for (int j = 0; j < FJB; j++)
        glds16(Bg + (size_t)j * 32 * KK + ko,
               Bs0 + (size_t)(cur ^ 1) * BN * 64 + (size_t)(wv * 8 + j * 32) * 64, lane);
    }

    const u16* Ac = As0 + (size_t)cur * BM * 64;
    const u16* Bc = Bs0 + (size_t)cur * BN * 64;
#pragma unroll
    for (int ks = 0; ks < 2; ks++) {
      half8 a[FIW], b[FJW];
#pragma unroll
      for (int i = 0; i < FIW; i++)
        a[i] = *(const half8*)(Ac + (size_t)(wm + i * 16 + mm) * 64 + (size_t)((ks * 4 + quad) ^ sw) * 8);
#pragma unroll
      for (int j = 0; j < FJW; j++)
        b[j] = *(const half8*)(Bc + (size_t)(wn + j * 16 + mm) * 64 + (size_t)((ks * 4 + quad) ^ sw) * 8);
#pragma unroll
      for (int i = 0; i < FIW; i++)
#pragma unroll
        for (int j = 0; j < FJW; j++)
          acc[i][j] = __builtin_amdgcn_mfma_f32_16x16x32_f16(a[i], b[j], acc[i][j], 0, 0, 0);
    }
    cur ^= 1;
  }

  if constexpr (EPI == 4) {
    if (n0 >= 1024) {
      // ---- V-only block: LDS-transposed coalesced epilogue ----
      __syncthreads();             // all LDS reads of As/Bs done
      u16* T = smem;               // [128][130] f16, 33,280 B (fits in 64KB)
      const int h0 = (n0 >> 6) & 7;
      const int b_ = m0 >> 11, s_base = m0 & 2047;
#pragma unroll
      for (int j = 0; j < FJW; j++) {
        const int cn = wn + j * 16 + mm;
        const float bias = b2[(n0 & 511) + cn];
#pragma unroll
        for (int i = 0; i < FIW; i++)
#pragma unroll
          for (int r = 0; r < 4; r++) {
            const int gl = wm + i * 16 + quad * 4 + r;
            T[gl * 130 + cn] = f2h(acc[i][j][r] + bias);
          }
      }
      __syncthreads();
      const int rr = tid >> 1, shalf = tid & 1;    // rr: output row (h,d); shalf: s half
      const int hh = rr >> 6, dd = rr & 63;
      u16* outp = (u16*)o2 + ((size_t)((b_ * 8 + h0 + hh) * 64 + dd)) * 2048
                + s_base + shalf * 64;
#pragma unroll
      for (int g = 0; g < 8; g++) {
        union { u16 u[8]; uint4 v; } pk;
#pragma unroll
        for (int e = 0; e < 8; e++) {
          const int inner = g * 8 + e;                       // s'' within 64
          const int sl = shalf * 64 + (((inner & 3) << 4) | (inner >> 2));  // inverse perm
          pk.u[e] = T[sl * 130 + rr];
        }
        *(uint4*)(outp + g * 8) = pk.v;
      }
      return;
    }
  }

#pragma unroll
  for (int j = 0; j < FJW; j++) {
    const int gn = n0 + wn + j * 16 + mm;
    if (EPI == 4) {
      const int which = gn >> 9, col = gn & 511, h = (gn >> 6) & 7, d = gn & 63;
      const float* bp = (which == 0) ? b0 : b1;
      const float bias = bp[col];
      u16* dst = (which == 0) ? (u16*)o0 : (u16*)o1;
#pragma unroll
      for (int i = 0; i < FIW; i++)
#pragma unroll
        for (int r = 0; r < 4; r++) {
          const int gm = m0 + wm + i * 16 + quad * 4 + r;
          const int b_ = gm >> 11, s_ = gm & 2047;
          const float val = acc[i][j][r] + bias;
          dst[((size_t)((b_ * 8 + h) * 2048 + s_)) * 64 + d] = f2h(val);
        }
    } else {
      const float bias = b0[gn];
#pragma unroll
      for (int i = 0; i < FIW; i++)
#pragma unroll
        for (int r = 0; r < 4; r++) {
          const int gm = m0 + wm + i * 16 + quad * 4 + r;
          const float val = acc[i][j][r] + bias;
          const size_t idx = (size_t)gm * NN + gn;
          if (EPI == 2) {
            ((float*)o0)[idx] = val + h2f(resid[idx]);
          } else {  // EPI == 3: exact-erf GELU -> f16
            const float z  = val * 0.70710678118654752f;
            const float az = fabsf(z);
            const float t  = __builtin_amdgcn_rcpf(1.0f + 0.3275911f * az);
            const float poly = t * (0.254829592f + t * (-0.284496736f +
                               t * (1.421413741f + t * (-1.453152027f + t * 1.061405429f))));
            const float e = __builtin_amdgcn_exp2f(-az * az * L2E);
            float erf_ = 1.0f - poly * e;
            erf_ = (z < 0.0f) ? -erf_ : erf_;
            ((u16*)o0)[idx] = f2h(val * 0.5f * (1.0f + erf_));
          }
        }
    }
  }
}

// ---------------------------------------------------------------------------
// Flash v7 (f16): 8 waves / 512 threads, 128 q-rows per block, grid (16,32).
// (round-4 code, verbatim: the round-5 unroll-2 experiment regressed and is
// reverted.) One 16KB K/V tile-stage serves 128 q; 8 waves per barrier.
// LDS: Kls 2x8KB + Vls 2x8KB + P 8x2KB = 48 KB.
// Issue order per iter: (1) softmax-operand prefetches FIRST (oldest in
// vmcnt FIFO), (2) staging DMAs second -> end-of-iter waits resolve at
// vmcnt(2), staging stays in flight until next barrier's vmcnt(0) drain.
// s_setprio(1) wraps both MFMA clusters (T5).
// Packed-f16 softmax; P stored permuted-k (k' = (k&15)*4 | k>>4), b64 writes,
// XOR-swizzled rows -> zero bank conflicts (verified round 2).
// TILED: 2 = pbT+invT, 1 = pbT only (inv on the fly), 0 = raw pb32.
// ---------------------------------------------------------------------------
template <int TILED>
__global__ __launch_bounds__(512) void flash4_kernel(
    const u16* __restrict__ Q, const u16* __restrict__ Kb, const u16* __restrict__ Vt,
    const u16* __restrict__ pbT, const u16* __restrict__ invT,
    const float* __restrict__ pb32,
    const float* __restrict__ maskE, const float* __restrict__ tsf,
    u16* __restrict__ ctx) {
  __shared__ __align__(16) u16 Kls[2][64 * 64];
  __shared__ __align__(16) u16 Vls[2][64 * 64];
  __shared__ __align__(16) u16 P[8][16 * 64];
  const int tid = threadIdx.x, lane = tid & 63, w = tid >> 6;   // w in [0,8)
  const int quad = lane >> 4, mm = lane & 15;
  const int bh = blockIdx.y, b_ = bh >> 3, h_ = bh & 7;
  const int q0 = blockIdx.x * 128 + w * 16;
  const size_t qk_base = (size_t)bh * 2048 * 64;
  const size_t v_base  = (size_t)bh * 64 * 2048;
  const int srow = lane >> 3, slot = lane & 7;
  const int chunk = slot ^ srow;
  const int sw = mm & 7;

  // staging: each wave stages 8 rows (w*8 + srow) of K and V per tile.
  const u16* Kgl = Kb + qk_base + (size_t)(w * 8 + srow) * 64 + chunk * 8;
  const u16* Vgl = Vt + v_base + (size_t)(w * 8 + srow) * 2048 + chunk * 8;

  // stage k-tile 0 into buffer 0 (issued before everything else)
  glds16(Kgl, &Kls[0][(w * 8) * 64], lane);
  glds16(Vgl, &Vls[0][(w * 8) * 64], lane);

  half8 aq[2];
#pragma unroll
  for (int t = 0; t < 2; t++)
    aq[t] = *(const half8*)(Q + qk_base + (size_t)(q0 + mm) * 64 + t * 32 + quad * 8);

  float tqf[4];
  if (TILED < 2) {
#pragma unroll
    for (int r = 0; r < 4; r++) tqf[r] = tsf[b_ * 2048 + q0 + quad * 4 + r];
  }

  float l_r[4] = {0.f, 0.f, 0.f, 0.f};
  float4v o[4];
#pragma unroll
  for (int ob = 0; ob < 4; ob++) o[ob] = f4zero();

  // prefetch tile-0 per-lane softmax operands
  ushort4 pbc[4], invc[4]; float tkc[4], mkc[4];
  if (TILED >= 1) {
#pragma unroll
    for (int r = 0; r < 4; r++)
      pbc[r] = *(const ushort4*)(pbT + ((size_t)(h_ * 32) * 2048 + q0 + quad * 4 + r) * 64 + mm * 4);
  }
  if (TILED == 2) {
#pragma unroll
    for (int r = 0; r < 4; r++)
      invc[r] = *(const ushort4*)(invT + ((size_t)(b_ * 32) * 2048 + q0 + quad * 4 + r) * 64 + mm * 4);
  } else {
#pragma unroll
    for (int nb = 0; nb < 4; nb++) tkc[nb] = tsf[b_ * 2048 + nb * 16 + mm];
  }
#pragma unroll
  for (int nb = 0; nb < 4; nb++) mkc[nb] = maskE[b_ * 2048 + nb * 16 + mm];

  int cur = 0;
  for (int kt = 0; kt < 32; kt++) {
    const int k0 = kt * 64;
    __syncthreads();   // drains prev iter's staging; buf[cur] ready for all waves

    // (1) softmax-operand prefetch for next tile — issued FIRST (oldest in
    //     vmcnt FIFO) so waiting on these leaves the staging DMAs in flight.
    const int kn = (kt < 31) ? kt + 1 : kt;
    ushort4 pbn[4], invn[4]; float tkn[4], mkn[4];
    if (TILED >= 1) {
#pragma unroll
      for (int r = 0; r < 4; r++)
        pbn[r] = *(const ushort4*)(pbT + ((size_t)(h_ * 32 + kn) * 2048 + q0 + quad * 4 + r) * 64 + mm * 4);
    }
    if (TILED == 2) {
#pragma unroll
      for (int r = 0; r < 4; r++)
        invn[r] = *(const ushort4*)(invT + ((size_t)(b_ * 32 + kn) * 2048 + q0 + quad * 4 + r) * 64 + mm * 4);
    } else {
#pragma unroll
      for (int nb = 0; nb < 4; nb++) tkn[nb] = tsf[b_ * 2048 + kn * 64 + nb * 16 + mm];
    }
#pragma unroll
    for (int nb = 0; nb < 4; nb++) mkn[nb] = maskE[b_ * 2048 + kn * 64 + nb * 16 + mm];

    // (2) stage next K/V tile — these 2 DMAs stay in flight until the next
    //     barrier's vmcnt(0) drain, overlapping this tile's full compute.
    if (kt < 31) {
      const size_t ko = (size_t)(kt + 1) * 4096;
      const size_t vo = (size_t)(kt + 1) * 64;
      glds16(Kgl + ko, &Kls[cur ^ 1][(w * 8) * 64], lane);
      glds16(Vgl + vo, &Vls[cur ^ 1][(w * 8) * 64], lane);
    }

    // (3) QK^T from LDS
    const u16* Kc = Kls[cur];
    float4v s[4];
    __builtin_amdgcn_s_setprio(1);
#pragma unroll
    for (int nb = 0; nb < 4; nb++) {
      const half8 kf0 = *(const half8*)(Kc + (size_t)(nb * 16 + mm) * 64 + (size_t)(quad ^ sw) * 8);
      const half8 kf1 = *(const half8*)(Kc + (size_t)(nb * 16 + mm) * 64 + (size_t)((4 + quad) ^ sw) * 8);
      s[nb] = __builtin_amdgcn_mfma_f32_16x16x32_f16(aq[0], kf0, f4zero(), 0, 0, 0);
      s[nb] = __builtin_amdgcn_mfma_f32_16x16x32_f16(aq[1], kf1, s[nb], 0, 0, 0);
    }
    __builtin_amdgcn_s_setprio(0);

    // (4) packed-f16 softmax + P write (b64, XOR-swizzled, permuted-k layout)
    const half2v mk01 = cvtpk(mkc[0], mkc[1]);
    const half2v mk23 = cvtpk(mkc[2], mkc[3]);
#pragma unroll
    for (int r = 0; r < 4; r++) {
      half2v pb01, pb23, iv01, iv23;
      if (TILED >= 1) {
        pb01 = *(const half2v*)&pbc[r].x;
        pb23 = *(const half2v*)&pbc[r].z;
      } else {
        float pv[4];
#pragma unroll
        for (int nb = 0; nb < 4; nb++)
          pv[nb] = pb32[((size_t)h_ * 2048 + q0 + quad * 4 + r) * 2048 + k0 + nb * 16 + mm] * L2E;
        pb01 = cvtpk(pv[0], pv[1]); pb23 = cvtpk(pv[2], pv[3]);
      }
      if (TILED == 2) {
        iv01 = *(const half2v*)&invc[r].x;
        iv23 = *(const half2v*)&invc[r].z;
      } else {
        float ivv[4];
#pragma unroll
        for (int nb = 0; nb < 4; nb++) {
          const float u = fmaxf(tqf[r] - tkc[nb], 0.f);
          ivv[nb] = fmaf(u, L2E, 86561.70245333781f) *
                    __builtin_amdgcn_rcpf(fmaf(u, 9.f, 480000.f));
        }
        iv01 = cvtpk(ivv[0], ivv[1]); iv23 = cvtpk(ivv[2], ivv[3]);
      }
      const half2v s01 = cvtpk(s[0][r], s[1][r]);
      const half2v s23 = cvtpk(s[2][r], s[3][r]);
      const half2v t01 = __builtin_elementwise_fma(s01, iv01, pb01 + mk01);
      const half2v t23 = __builtin_elementwise_fma(s23, iv23, pb23 + mk23);
      half2v p01, p23;
      p01.x = hexp2_(t01.x); p01.y = hexp2_(t01.y);
      p23.x = hexp2_(t23.x); p23.y = hexp2_(t23.y);
      l_r[r] = fdot2f(p01, l_r[r]);
      l_r[r] = fdot2f(p23, l_r[r]);
      const int prow = quad * 4 + r;
      union { half2v h2[2]; half4v h4; } uu;
      uu.h2[0] = p01; uu.h2[1] = p23;
      *(half4v*)((char*)P[w] + prow * 128 + ((mm * 8) ^ ((prow & 7) << 4))) = uu.h4;
    }

    // (5) PV from LDS (A = P in permuted-k storage, B = V with matching k order)
    const u16* Vc = Vls[cur];
    const char* Pb = (const char*)P[w] + mm * 128;
    const int pxor = (mm & 7) << 4;
    const half8 ap0 = *(const half8*)(Pb + ((quad * 16) ^ pxor));
    const half8 ap1 = *(const half8*)(Pb + ((64 + quad * 16) ^ pxor));
    __builtin_amdgcn_s_setprio(1);
#pragma unroll
    for (int ob = 0; ob < 4; ob++) {
      const half8 vf0 = *(const half8*)(Vc + (size_t)(ob * 16 + mm) * 64 + (size_t)(quad ^ sw) * 8);
      const half8 vf1 = *(const half8*)(Vc + (size_t)(ob * 16 + mm) * 64 + (size_t)((4 + quad) ^ sw) * 8);
      o[ob] = __builtin_amdgcn_mfma_f32_16x16x32_f16(ap0, vf0, o[ob], 0, 0, 0);
      o[ob] = __builtin_amdgcn_mfma_f32_16x16x32_f16(ap1, vf1, o[ob], 0, 0, 0);
    }
    __builtin_amdgcn_s_setprio(0);

    // (6) rotate prefetched operands (waits vmcnt(2): staging stays in flight)
#pragma unroll
    for (int r = 0; r < 4; r++) { pbc[r] = pbn[r]; invc[r] = invn[r]; }
#pragma unroll
    for (int nb = 0; nb < 4; nb++) { tkc[nb] = tkn[nb]; mkc[nb] = mkn[nb]; }
    cur ^= 1;
  }

#pragma unroll
  for (int r = 0; r < 4; r++) {
    float l = l_r[r];
#pragma unroll
    for (int sh = 1; sh < 16; sh <<= 1) l += __shfl_xor(l, sh, 64);  // sum over mm within quad-group
    const float rl = __builtin_amdgcn_rcpf(l);
    const int qrow = q0 + quad * 4 + r;
#pragma unroll
    for (int ob = 0; ob < 4; ob++)
      ctx[((size_t)b_ * 2048 + qrow) * 512 + h_ * 64 + ob * 16 + mm] = f2h(o[ob][r] * rl);
  }
}

// ---------------------------------------------------------------------------
// LayerNorm over H=512: 1 wave/row, 4 rows/block. f16 out always, f32 optional.
// ---------------------------------------------------------------------------
__global__ __launch_bounds__(256) void ln_kernel(
    const float* __restrict__ in, const float* __restrict__ g, const float* __restrict__ bb,
    float* __restrict__ of, u16* __restrict__ obf) {
  const int lane = threadIdx.x & 63, w = threadIdx.x >> 6;
  const int row = blockIdx.x * 4 + w;
  const float* x = in + (size_t)row * 512;
  float v[8];
  const float4 t0 = *(const float4*)(x + lane * 8);
  const float4 t1 = *(const float4*)(x + lane * 8 + 4);
  v[0] = t0.x; v[1] = t0.y; v[2] = t0.z; v[3] = t0.w;
  v[4] = t1.x; v[5] = t1.y; v[6] = t1.z; v[7] = t1.w;
  float s = 0.f;
#pragma unroll
  for (int i = 0; i < 8; i++) s += v[i];
#pragma unroll
  for (int sh = 1; sh < 64; sh <<= 1) s += __shfl_xor(s, sh, 64);
  const float mean = s * (1.0f / 512.0f);
  float sq = 0.f;
#pragma unroll
  for (int i = 0; i < 8; i++) { const float d = v[i] - mean; sq += d * d; }
#pragma unroll
  for (int sh = 1; sh < 64; sh <<= 1) sq += __shfl_xor(sq, sh, 64);
  const float rstd = rsqrtf(sq * (1.0f / 512.0f) + 1e-12f);
#pragma unroll
  for (int i = 0; i < 8; i++) {
    const int col = lane * 8 + i;
    const float y = (v[i] - mean) * rstd * g[col] + bb[col];
    if (of) of[(size_t)row * 512 + col] = y;
    obf[(size_t)row * 512 + col] = f2h(y);
  }
}

// ---------------------------------------------------------------------------
extern "C" void kernel_launch(void* const* d_in, const int* in_sizes, int n_in,
                              void* d_out, int out_size, void* d_ws, size_t ws_size,
                              hipStream_t stream) {
  const float* x_in = (const float*)d_in[0];
  const float* mask = (const float*)d_in[1];
  const float* pb   = (const float*)d_in[2];
  const int*   ts   = (const int*)d_in[3];
  const float* wq = (const float*)d_in[4];  const float* bq = (const float*)d_in[5];
  const float* wk = (const float*)d_in[6];  const float* bk = (const float*)d_in[7];
  const float* wvp = (const float*)d_in[8]; const float* bv = (const float*)d_in[9];
  const float* wo = (const float*)d_in[10]; const float* bo = (const float*)d_in[11];
  const float* ln1g = (const float*)d_in[12]; const float* ln1b = (const float*)d_in[13];
  const float* wi = (const float*)d_in[14]; const float* bi = (const float*)d_in[15];
  const float* wo2 = (const float*)d_in[16]; const float* bo2 = (const float*)d_in[17];
  const float* ln2g = (const float*)d_in[18]; const float* ln2b = (const float*)d_in[19];

  char* ws = (char*)d_ws;
  const size_t o_wqkv  = 0;
  const size_t o_woT   = 6291456;
  const size_t o_wiT   = 8388608;
  const size_t o_wo2T  = 16777216;
  const size_t o_maskE = 25165824;
  const size_t o_tsf   = 25198592;
  const size_t o_xbf   = 25231360;
  const size_t o_qb    = 33619968;
  const size_t o_kb    = 42008576;
  const size_t o_vb    = 50397184;
  const size_t o_ctx   = 58785792;
  const size_t o_attnb = 67174400;
  const size_t o_tmp   = 75563008;
  const size_t o_pbT   = 92340224;    // 67,108,864 B
  const size_t o_invT  = 159449088;   // 33,554,432 B
  const int tiled = (ws_size >= o_invT + 33554432ull) ? 2
                  : (ws_size >= o_pbT + 67108864ull) ? 1 : 0;

  u16*   wqkvT = (u16*)(ws + o_wqkv);
  u16*   woT   = (u16*)(ws + o_woT);
  u16*   wiT   = (u16*)(ws + o_wiT);
  u16*   wo2T  = (u16*)(ws + o_wo2T);
  float* maskE = (float*)(ws + o_maskE);
  float* tsf   = (float*)(ws + o_tsf);
  u16*   xbf   = (u16*)(ws + o_xbf);
  u16*   qb    = (u16*)(ws + o_qb);
  u16*   kb    = (u16*)(ws + o_kb);
  u16*   vb    = (u16*)(ws + o_vb);
  u16*   ctx   = (u16*)(ws + o_ctx);
  u16*   hb    = (u16*)(ws + o_qb);
  u16*   attnb = (u16*)(ws + o_attnb);
  float* tmp   = (float*)(ws + o_tmp);
  u16*   pbT   = (u16*)(ws + o_pbT);
  u16*   invT  = (u16*)(ws + o_invT);

  const dim3 blk(256);
  const dim3 blk512(512);
  transpose_cast_kernel<<<dim3(16, 16, 4), blk, 0, stream>>>(wq,  wqkvT,          512, 512, 786432);
  transpose_cast_kernel<<<dim3(16, 16, 4), blk, 0, stream>>>(wk,  wqkvT + 262144, 512, 512, 786432);
  transpose_cast_kernel<<<dim3(16, 16, 4), blk, 0, stream>>>(wvp, wqkvT + 524288, 512, 512, 786432);
  transpose_cast_kernel<<<dim3(16, 16, 4), blk, 0, stream>>>(wo,  woT,  512, 512,  262144);
  transpose_cast_kernel<<<dim3(64, 16, 4), blk, 0, stream>>>(wi,  wiT,  512, 2048, 1048576);
  transpose_cast_kernel<<<dim3(16, 64, 4), blk, 0, stream>>>(wo2, wo2T, 2048, 512, 1048576);
  maskts_kernel<<<32, blk, 0, stream>>>(mask, ts, maskE, tsf);
  cast_kernel<<<4096, blk, 0, stream>>>(x_in, xbf);
  if (tiled >= 1) pb_tile_kernel<<<32768, blk, 0, stream>>>(pb, pbT);
  if (tiled == 2) inv_tile_kernel<<<16384, blk, 0, stream>>>(ts, invT);

  for (int l = 0; l < 4; l++) {
    gemm_kernel<128, 128, 1536, 512, 4><<<dim3(64, 12), blk, 0, stream>>>(
        xbf, wqkvT + (size_t)l * 786432, bq + l * 512, bk + l * 512, bv + l * 512,
        nullptr, qb, kb, vb);
    if (tiled == 2)
      flash4_kernel<2><<<dim3(16, 32), blk512, 0, stream>>>(qb, kb, vb, pbT, invT, pb, maskE, tsf, ctx);
    else if (tiled == 1)
      flash4_kernel<1><<<dim3(16, 32), blk512, 0, stream>>>(qb, kb, vb, pbT, nullptr, pb, maskE, tsf, ctx);
    else
      flash4_kernel<0><<<dim3(16, 32), blk512, 0, stream>>>(qb, kb, vb, nullptr, nullptr, pb, maskE, tsf, ctx);
    gemm_kernel<128, 64, 512, 512, 2><<<dim3(64, 8), blk, 0, stream>>>(
        ctx, woT + (size_t)l * 262144, bo + l * 512, nullptr, nullptr, xbf,
        tmp, nullptr, nullptr);
    ln_kernel<<<2048, blk, 0, stream>>>(tmp, ln1g + l * 512, ln1b + l * 512, nullptr, attnb);
    gemm_kernel<128, 128, 2048, 512, 3><<<dim3(64, 16), blk, 0, stream>>>(
        attnb, wiT + (size_t)l * 1048576, bi + l * 2048, nullptr, nullptr, nullptr,
        hb, nullptr, nullptr);
    gemm_kernel<128, 64, 512, 2048, 2><<<dim3(64, 8), blk, 0, stream>>>(
        hb, wo2T + (size_t)l * 1048576, bo2 + l * 512, nullptr, nullptr, attnb,
        tmp, nullptr, nullptr);
    ln_kernel<<<2048, blk, 0, stream>>>(tmp, ln2g + l * 512, ln2b + l * 512,
                                        (l == 3) ? (float*)d_out : nullptr, xbf);
  }
  (void)in_sizes; (void)n_in; (void)out_size;
}

// Round 7
// 1122.840 us; speedup vs baseline: 1.2399x; 1.0321x over previous
//
#include <hip/hip_runtime.h>
#include <stdint.h>

typedef unsigned short u16;
using half8   = __attribute__((ext_vector_type(8))) _Float16;
using half4v  = __attribute__((ext_vector_type(4))) _Float16;
using half2v  = __attribute__((ext_vector_type(2))) _Float16;
using float4v = __attribute__((ext_vector_type(4))) float;

#define L2E 1.4426950408889634f

__device__ inline float4v f4zero() { float4v z = {0.f, 0.f, 0.f, 0.f}; return z; }

__device__ inline u16 f2h(float f) {
  union { _Float16 h; u16 u; } v; v.h = (_Float16)f; return v.u;
}
__device__ inline float h2f(u16 u) {
  union { u16 u; _Float16 h; } v; v.u = u; return (float)v.h;
}

__device__ inline half2v cvtpk(float a, float b) {
  return __builtin_bit_cast(half2v, __builtin_amdgcn_cvt_pkrtz(a, b));
}
// f16 exp2 via VOP1 v_exp_f16 (self-contained; no OCML/builtin dependency)
__device__ inline _Float16 hexp2_(_Float16 x) {
  _Float16 r;
  asm("v_exp_f16 %0, %1" : "=v"(r) : "v"(x));
  return r;
}
// l += p.x + p.y with f32 accumulate (v_dot2_f32_f16 against (1,1))
__device__ inline float fdot2f(half2v a, float c) {
#if __has_builtin(__builtin_amdgcn_fdot2)
  typedef __attribute__((ext_vector_type(2))) __fp16 h2r;
  return __builtin_amdgcn_fdot2(__builtin_bit_cast(h2r, a),
                                __builtin_bit_cast(h2r, 0x3C003C00u), c, false);
#else
  return c + (float)a.x + (float)a.y;
#endif
}

// async global->LDS, 16B/lane. LDS dest = wave-uniform base + lane*16 (HW).
__device__ inline void glds16(const u16* g, u16* lds_base, int lane) {
#if __has_builtin(__builtin_amdgcn_global_load_lds)
  (void)lane;
  __builtin_amdgcn_global_load_lds((const __attribute__((address_space(1))) void*)g,
                                   (__attribute__((address_space(3))) void*)lds_base,
                                   16, 0, 0);
#else
  *(uint4*)(lds_base + (size_t)lane * 8) = *(const uint4*)g;
#endif
}

// ---------------------------------------------------------------------------
// fp32 (K,N) row-major -> f16 (N,K) row-major, per-layer stride out_ls elems.
// ---------------------------------------------------------------------------
__global__ __launch_bounds__(256) void transpose_cast_kernel(
    const float* __restrict__ in, u16* __restrict__ out, int K, int N, size_t out_ls) {
  __shared__ float tile[32][33];
  const int tx = threadIdx.x & 31, ty = threadIdx.x >> 5;
  in  += (size_t)blockIdx.z * K * N;
  out += (size_t)blockIdx.z * out_ls;
  const int n  = blockIdx.x * 32 + tx;
  const int k0 = blockIdx.y * 32;
#pragma unroll
  for (int j = 0; j < 32; j += 8)
    tile[ty + j][tx] = in[(size_t)(k0 + ty + j) * N + n];
  __syncthreads();
  const int k = k0 + tx;
  const int n0 = blockIdx.x * 32;
#pragma unroll
  for (int j = 0; j < 32; j += 8)
    out[(size_t)(n0 + ty + j) * K + k] = f2h(tile[tx][ty + j]);
}

__global__ __launch_bounds__(256) void cast_kernel(const float* __restrict__ in,
                                                   u16* __restrict__ out) {
  const int i = (blockIdx.x * 256 + threadIdx.x) * 4;
  float4 t = *(const float4*)(in + i);
  ushort4 o;
  o.x = f2h(t.x); o.y = f2h(t.y); o.z = f2h(t.z); o.w = f2h(t.w);
  *(ushort4*)(out + i) = o;
}

// pb fp32 (1,8,2048,2048) -> pbT f16 [8][32][2048][64] perm pos=mm*4+nb, *L2E
__global__ __launch_bounds__(256) void pb_tile_kernel(const float* __restrict__ pb,
                                                      u16* __restrict__ pbT) {
  const int g  = blockIdx.x * 256 + threadIdx.x;
  const int mm = g & 15;
  const int q  = (g >> 4) & 2047;
  const int kbh = g >> 15;
  const int kb = kbh & 31, h = kbh >> 5;
  const float* src = pb + ((size_t)h * 2048 + q) * 2048 + kb * 64 + mm;
  ushort4 o;
  o.x = f2h(src[0]  * L2E);
  o.y = f2h(src[16] * L2E);
  o.z = f2h(src[32] * L2E);
  o.w = f2h(src[48] * L2E);
  *(ushort4*)(pbT + ((size_t)(h * 32 + kb) * 2048 + q) * 64 + mm * 4) = o;
}

// lag scale inv (head- and layer-independent) -> invT f16 [4][32][2048][64],
// perm pos=mm*4+nb, with L2E folded in.  inv = (u+60000)/(9u+480000), u>=0.
__global__ __launch_bounds__(256) void inv_tile_kernel(const int* __restrict__ ts,
                                                       u16* __restrict__ invT) {
  const int g  = blockIdx.x * 256 + threadIdx.x;   // 4*32*2048*16 = 2^22
  const int mm = g & 15;
  const int q  = (g >> 4) & 2047;
  const int kb = (g >> 15) & 31;
  const int b  = g >> 20;
  const int tq = ts[b * 2048 + q];
  ushort4 o;
  u16* op = (u16*)&o;
#pragma unroll
  for (int nb = 0; nb < 4; nb++) {
    const int k = kb * 64 + nb * 16 + mm;
    const int du = tq - ts[b * 2048 + k];
    const float u = (du > 0) ? (float)du : 0.f;
    op[nb] = f2h(fmaf(u, L2E, 86561.70245333781f) *
                 __builtin_amdgcn_rcpf(fmaf(u, 9.f, 480000.f)));
  }
  *(ushort4*)(invT + ((size_t)(b * 32 + kb) * 2048 + q) * 64 + mm * 4) = o;
}

__global__ __launch_bounds__(256) void maskts_kernel(const float* __restrict__ mask,
                                                     const int* __restrict__ ts,
                                                     float* __restrict__ maskE,
                                                     float* __restrict__ tsf) {
  const int i = blockIdx.x * 256 + threadIdx.x;
  maskE[i] = mask[i] * L2E;
  tsf[i]   = (float)ts[i];
}

// ---------------------------------------------------------------------------
// GEMM (256 threads, 4 waves) C[M,N] = A[M,K]*Wt^T. BMxBN tile, BK=64.
// Used for AO / FFN2 (EPI=2: fp32 out = acc+bias+f16 resid).
// ---------------------------------------------------------------------------
template <int BM, int BN, int NN, int KK, int EPI>
__global__ __launch_bounds__(256) void gemm_kernel(
    const u16* __restrict__ A, const u16* __restrict__ Wt,
    const float* __restrict__ b0, const float* __restrict__ b1, const float* __restrict__ b2,
    const u16* __restrict__ resid,
    void* __restrict__ o0, void* __restrict__ o1, void* __restrict__ o2) {
  constexpr int FI = BM / 32;
  constexpr int FJB = BN / 32;
  constexpr int FIW = BM / 32;
  constexpr int FJW = BN / 32;
  constexpr int NT = KK / 64;
  __shared__ __align__(16) u16 smem[2 * BM * 64 + 2 * BN * 64];
  u16* As0 = smem;                 // [2][BM*64]
  u16* Bs0 = smem + 2 * BM * 64;   // [2][BN*64]
  const int tid = threadIdx.x, lane = tid & 63, wv = tid >> 6;
  const int quad = lane >> 4, mm = lane & 15;
  const int m0 = blockIdx.x * BM, n0 = blockIdx.y * BN;
  const int wm = (wv >> 1) * (BM / 2), wn = (wv & 1) * (BN / 2);
  const int srow = tid >> 3, slot = tid & 7;
  const int chunk = slot ^ (srow & 7);
  const u16* Ag = A  + (size_t)(m0 + srow) * KK + chunk * 8;
  const u16* Bg = Wt + (size_t)(n0 + srow) * KK + chunk * 8;
  const int sw = mm & 7;

  float4v acc[FIW][FJW];
#pragma unroll
  for (int i = 0; i < FIW; i++)
#pragma unroll
    for (int j = 0; j < FJW; j++) acc[i][j] = f4zero();

  // prologue: stage k-tile 0 into buffer 0
#pragma unroll
  for (int i = 0; i < FI; i++)
    glds16(Ag + (size_t)i * 32 * KK, As0 + (size_t)(wv * 8 + i * 32) * 64, lane);
#pragma unroll
  for (int j = 0; j < FJB; j++)
    glds16(Bg + (size_t)j * 32 * KK, Bs0 + (size_t)(wv * 8 + j * 32) * 64, lane);

  int cur = 0;
#pragma unroll 2
  for (int kt = 0; kt < NT; kt++) {
    __syncthreads();   // buf[cur] staged & drained; prior readers of buf[cur^1] done

    // issue next tile's staging immediately -> overlaps this tile's compute
    if (kt + 1 < NT) {
      const size_t ko = (size_t)(kt + 1) * 64;
#pragma unroll
      for (int i = 0; i < FI; i++)
        glds16(Ag + (size_t)i * 32 * KK + ko,
               As0 + (size_t)(cur ^ 1) * BM * 64 + (size_t)(wv * 8 + i * 32) * 64, lane);
#pragma unroll
      for (int j = 0; j < FJB; j++)
        glds16(Bg + (size_t)j * 32 * KK + ko,
               Bs0 + (size_t)(cur ^ 1) * BN * 64 + (size_t)(wv * 8 + j * 32) * 64, lane);
    }

    const u16* Ac = As0 + (size_t)cur * BM * 64;
    const u16* Bc = Bs0 + (size_t)cur * BN * 64;
#pragma unroll
    for (int ks = 0; ks < 2; ks++) {
      half8 a[FIW], b[FJW];
#pragma unroll
      for (int i = 0; i < FIW; i++)
        a[i] = *(const half8*)(Ac + (size_t)(wm + i * 16 + mm) * 64 + (size_t)((ks * 4 + quad) ^ sw) * 8);
#pragma unroll
      for (int j = 0; j < FJW; j++)
        b[j] = *(const half8*)(Bc + (size_t)(wn + j * 16 + mm) * 64 + (size_t)((ks * 4 + quad) ^ sw) * 8);
#pragma unroll
      for (int i = 0; i < FIW; i++)
#pragma unroll
        for (int j = 0; j < FJW; j++)
          acc[i][j] = __builtin_amdgcn_mfma_f32_16x16x32_f16(a[i], b[j], acc[i][j], 0, 0, 0);
    }
    cur ^= 1;
  }

#pragma unroll
  for (int j = 0; j < FJW; j++) {
    const int gn = n0 + wn + j * 16 + mm;
    const float bias = b0[gn];
#pragma unroll
    for (int i = 0; i < FIW; i++)
#pragma unroll
      for (int r = 0; r < 4; r++) {
        const int gm = m0 + wm + i * 16 + quad * 4 + r;
        const float val = acc[i][j][r] + bias;
        const size_t idx = (size_t)gm * NN + gn;
        if (EPI == 2) {
          ((float*)o0)[idx] = val + h2f(resid[idx]);
        } else {  // EPI == 3: exact-erf GELU -> f16
          const float z  = val * 0.70710678118654752f;
          const float az = fabsf(z);
          const float t  = __builtin_amdgcn_rcpf(1.0f + 0.3275911f * az);
          const float poly = t * (0.254829592f + t * (-0.284496736f +
                             t * (1.421413741f + t * (-1.453152027f + t * 1.061405429f))));
          const float e = __builtin_amdgcn_exp2f(-az * az * L2E);
          float erf_ = 1.0f - poly * e;
          erf_ = (z < 0.0f) ? -erf_ : erf_;
          ((u16*)o0)[idx] = f2h(val * 0.5f * (1.0f + erf_));
        }
      }
  }
  (void)b1; (void)b2; (void)o1; (void)o2;
}

// ---------------------------------------------------------------------------
// GEMM8 (512 threads, 8 waves): BM=256, BN=128, BK=64 single-buffered.
// 256x128 tile -> 85 FLOP per staged byte (above the 72 FLOP/B L2 knee that
// limits the 128x128 tile). Per-wave inner loop identical to gemm_kernel
// (FIW=FJW=4, 32 MFMA/iter); waves 4x2 over the tile. LDS 48 KB.
// EPI: 3 = gelu(acc+bias) f16 (FFN1);
//      4 = fused QKV scatter: Q,K scatter as before; V (n0>=1024) via
//          TWO-PASS LDS transpose (T[128][130] per m-half) with the
//          64-token inverse permutation, coalesced 16B stores.
// ---------------------------------------------------------------------------
template <int NN, int KK, int EPI>
__global__ __launch_bounds__(512) void gemm8_kernel(
    const u16* __restrict__ A, const u16* __restrict__ Wt,
    const float* __restrict__ b0, const float* __restrict__ b1, const float* __restrict__ b2,
    void* __restrict__ o0, void* __restrict__ o1, void* __restrict__ o2) {
  __shared__ __align__(16) u16 smem[256 * 64 + 128 * 64];   // As | Bs, 48 KB
  u16* As = smem;
  u16* Bs = smem + 256 * 64;
  const int tid = threadIdx.x, lane = tid & 63, wv = tid >> 6;  // wv in [0,8)
  const int quad = lane >> 4, mm = lane & 15;
  const int m0 = blockIdx.x * 256, n0 = blockIdx.y * 128;
  const int wm = (wv >> 1) * 64, wn = (wv & 1) * 64;
  const int srow = tid >> 3, slot = tid & 7;                    // srow in [0,64)
  const int chunk = slot ^ (srow & 7);
  const u16* Ag = A  + (size_t)(m0 + srow) * KK + chunk * 8;
  const u16* Bg = Wt + (size_t)(n0 + srow) * KK + chunk * 8;
  const int sw = mm & 7;

  float4v acc[4][4];
#pragma unroll
  for (int i = 0; i < 4; i++)
#pragma unroll
    for (int j = 0; j < 4; j++) acc[i][j] = f4zero();

  for (int kte = 0; kte < KK; kte += 64) {
    // stage: A 256 rows (4 passes), B 128 rows (2 passes); 6 DMAs/thread
#pragma unroll
    for (int p = 0; p < 4; p++)
      glds16(Ag + (size_t)(p * 64) * KK + kte, As + (size_t)(p * 64 + wv * 8) * 64, lane);
#pragma unroll
    for (int p = 0; p < 2; p++)
      glds16(Bg + (size_t)(p * 64) * KK + kte, Bs + (size_t)(p * 64 + wv * 8) * 64, lane);
    __syncthreads();   // staging drained

#pragma unroll
    for (int ks = 0; ks < 2; ks++) {
      half8 a[4], b[4];
#pragma unroll
      for (int i = 0; i < 4; i++)
        a[i] = *(const half8*)(As + (size_t)(wm + i * 16 + mm) * 64 + (size_t)((ks * 4 + quad) ^ sw) * 8);
#pragma unroll
      for (int j = 0; j < 4; j++)
        b[j] = *(const half8*)(Bs + (size_t)(wn + j * 16 + mm) * 64 + (size_t)((ks * 4 + quad) ^ sw) * 8);
#pragma unroll
      for (int i = 0; i < 4; i++)
#pragma unroll
        for (int j = 0; j < 4; j++)
          acc[i][j] = __builtin_amdgcn_mfma_f32_16x16x32_f16(a[i], b[j], acc[i][j], 0, 0, 0);
    }
    __syncthreads();   // readers done before next overwrite
  }

  if constexpr (EPI == 4) {
    if (n0 >= 1024) {
      // ---- V block (BN=128 spans 2 heads): two-pass LDS transpose ----
      const int b_ = m0 >> 11, s_base = m0 & 2047;
      const int h0 = (n0 >> 6) & 7;
      u16* T = smem;   // [128][130] f16 = 33,280 B <= 48 KB
#pragma unroll
      for (int hp = 0; hp < 2; hp++) {
        __syncthreads();           // prior T readers (or LDS readers) done
        if ((wv >> 2) == hp) {     // waves whose wm is in this m-half
          const int lm = wm & 127; // 0 or 64
#pragma unroll
          for (int j = 0; j < 4; j++) {
            const int cn = wn + j * 16 + mm;
            const float bias = b2[(n0 & 511) + cn];
#pragma unroll
            for (int i = 0; i < 4; i++)
#pragma unroll
              for (int r = 0; r < 4; r++)
                T[(lm + i * 16 + quad * 4 + r) * 130 + cn] = f2h(acc[i][j][r] + bias);
          }
        }
        __syncthreads();
        // store this 128-token half: rr = output (hh,dd) col, sq = s quarter
        const int rr = tid >> 2, sq = tid & 3;
        const int hh = rr >> 6, dd = rr & 63;
        u16* outp = (u16*)o2 + ((size_t)((b_ * 8 + h0 + hh) * 64 + dd)) * 2048
                  + s_base + hp * 128 + sq * 32;
#pragma unroll
        for (int g = 0; g < 4; g++) {
          union { u16 u[8]; uint4 v; } pk;
#pragma unroll
          for (int e = 0; e < 8; e++) {
            const int sl = sq * 32 + g * 8 + e;   // output array offset in [0,128)
            const int tl = (sl & 64) + (((sl & 3) << 4) | ((sl & 63) >> 2));
            pk.u[e] = T[tl * 130 + rr];
          }
          *(uint4*)(outp + g * 8) = pk.v;
        }
      }
      return;
    }
    // ---- Q/K scatter ----
#pragma unroll
    for (int j = 0; j < 4; j++) {
      const int gn = n0 + wn + j * 16 + mm;
      const int which = gn >> 9, col = gn & 511, h = (gn >> 6) & 7, d = gn & 63;
      const float* bp = (which == 0) ? b0 : b1;
      const float bias = bp[col];
      u16* dst = (which == 0) ? (u16*)o0 : (u16*)o1;
#pragma unroll
      for (int i = 0; i < 4; i++)
#pragma unroll
        for (int r = 0; r < 4; r++) {
          const int gm = m0 + wm + i * 16 + quad * 4 + r;
          const int b_ = gm >> 11, s_ = gm & 2047;
          dst[((size_t)((b_ * 8 + h) * 2048 + s_)) * 64 + d] = f2h(acc[i][j][r] + bias);
        }
    }
    return;
  }

  // EPI == 3: exact-erf GELU -> f16
#pragma unroll
  for (int j = 0; j < 4; j++) {
    const int gn = n0 + wn + j * 16 + mm;
    const float bias = b0[gn];
#pragma unroll
    for (int i = 0; i < 4; i++)
#pragma unroll
      for (int r = 0; r < 4; r++) {
        const int gm = m0 + wm + i * 16 + quad * 4 + r;
        const float val = acc[i][j][r] + bias;
        const size_t idx = (size_t)gm * NN + gn;
        const float z  = val * 0.70710678118654752f;
        const float az = fabsf(z);
        const float t  = __builtin_amdgcn_rcpf(1.0f + 0.3275911f * az);
        const float poly = t * (0.254829592f + t * (-0.284496736f +
                           t * (1.421413741f + t * (-1.453152027f + t * 1.061405429f))));
        const float e = __builtin_amdgcn_exp2f(-az * az * L2E);
        float erf_ = 1.0f - poly * e;
        erf_ = (z < 0.0f) ? -erf_ : erf_;
        ((u16*)o0)[idx] = f2h(val * 0.5f * (1.0f + erf_));
      }
  }
}

// ---------------------------------------------------------------------------
// Flash v7 (f16): 8 waves / 512 threads, 128 q-rows per block, grid (16,32).
// (round-4/6 code, verbatim — known-good at ~86 us.)
// ---------------------------------------------------------------------------
template <int TILED>
__global__ __launch_bounds__(512) void flash4_kernel(
    const u16* __restrict__ Q, const u16* __restrict__ Kb, const u16* __restrict__ Vt,
    const u16* __restrict__ pbT, const u16* __restrict__ invT,
    const float* __restrict__ pb32,
    const float* __restrict__ maskE, const float* __restrict__ tsf,
    u16* __restrict__ ctx) {
  __shared__ __align__(16) u16 Kls[2][64 * 64];
  __shared__ __align__(16) u16 Vls[2][64 * 64];
  __shared__ __align__(16) u16 P[8][16 * 64];
  const int tid = threadIdx.x, lane = tid & 63, w = tid >> 6;   // w in [0,8)
  const int quad = lane >> 4, mm = lane & 15;
  const int bh = blockIdx.y, b_ = bh >> 3, h_ = bh & 7;
  const int q0 = blockIdx.x * 128 + w * 16;
  const size_t qk_base = (size_t)bh * 2048 * 64;
  const size_t v_base  = (size_t)bh * 64 * 2048;
  const int srow = lane >> 3, slot = lane & 7;
  const int chunk = slot ^ srow;
  const int sw = mm & 7;

  // staging: each wave stages 8 rows (w*8 + srow) of K and V per tile.
  const u16* Kgl = Kb + qk_base + (size_t)(w * 8 + srow) * 64 + chunk * 8;
  const u16* Vgl = Vt + v_base + (size_t)(w * 8 + srow) * 2048 + chunk * 8;

  // stage k-tile 0 into buffer 0 (issued before everything else)
  glds16(Kgl, &Kls[0][(w * 8) * 64], lane);
  glds16(Vgl, &Vls[0][(w * 8) * 64], lane);

  half8 aq[2];
#pragma unroll
  for (int t = 0; t < 2; t++)
    aq[t] = *(const half8*)(Q + qk_base + (size_t)(q0 + mm) * 64 + t * 32 + quad * 8);

  float tqf[4];
  if (TILED < 2) {
#pragma unroll
    for (int r = 0; r < 4; r++) tqf[r] = tsf[b_ * 2048 + q0 + quad * 4 + r];
  }

  float l_r[4] = {0.f, 0.f, 0.f, 0.f};
  float4v o[4];
#pragma unroll
  for (int ob = 0; ob < 4; ob++) o[ob] = f4zero();

  // prefetch tile-0 per-lane softmax operands
  ushort4 pbc[4], invc[4]; float tkc[4], mkc[4];
  if (TILED >= 1) {
#pragma unroll
    for (int r = 0; r < 4; r++)
      pbc[r] = *(const ushort4*)(pbT + ((size_t)(h_ * 32) * 2048 + q0 + quad * 4 + r) * 64 + mm * 4);
  }
  if (TILED == 2) {
#pragma unroll
    for (int r = 0; r < 4; r++)
      invc[r] = *(const ushort4*)(invT + ((size_t)(b_ * 32) * 2048 + q0 + quad * 4 + r) * 64 + mm * 4);
  } else {
#pragma unroll
    for (int nb = 0; nb < 4; nb++) tkc[nb] = tsf[b_ * 2048 + nb * 16 + mm];
  }
#pragma unroll
  for (int nb = 0; nb < 4; nb++) mkc[nb] = maskE[b_ * 2048 + nb * 16 + mm];

  int cur = 0;
  for (int kt = 0; kt < 32; kt++) {
    const int k0 = kt * 64;
    __syncthreads();   // drains prev iter's staging; buf[cur] ready for all waves

    // (1) softmax-operand prefetch for next tile — issued FIRST (oldest in
    //     vmcnt FIFO) so waiting on these leaves the staging DMAs in flight.
    const int kn = (kt < 31) ? kt + 1 : kt;
    ushort4 pbn[4], invn[4]; float tkn[4], mkn[4];
    if (TILED >= 1) {
#pragma unroll
      for (int r = 0; r < 4; r++)
        pbn[r] = *(const ushort4*)(pbT + ((size_t)(h_ * 32 + kn) * 2048 + q0 + quad * 4 + r) * 64 + mm * 4);
    }
    if (TILED == 2) {
#pragma unroll
      for (int r = 0; r < 4; r++)
        invn[r] = *(const ushort4*)(invT + ((size_t)(b_ * 32 + kn) * 2048 + q0 + quad * 4 + r) * 64 + mm * 4);
    } else {
#pragma unroll
      for (int nb = 0; nb < 4; nb++) tkn[nb] = tsf[b_ * 2048 + kn * 64 + nb * 16 + mm];
    }
#pragma unroll
    for (int nb = 0; nb < 4; nb++) mkn[nb] = maskE[b_ * 2048 + kn * 64 + nb * 16 + mm];

    // (2) stage next K/V tile — these 2 DMAs stay in flight until the next
    //     barrier's vmcnt(0) drain, overlapping this tile's full compute.
    if (kt < 31) {
      const size_t ko = (size_t)(kt + 1) * 4096;
      const size_t vo = (size_t)(kt + 1) * 64;
      glds16(Kgl + ko, &Kls[cur ^ 1][(w * 8) * 64], lane);
      glds16(Vgl + vo, &Vls[cur ^ 1][(w * 8) * 64], lane);
    }

    // (3) QK^T from LDS
    const u16* Kc = Kls[cur];
    float4v s[4];
    __builtin_amdgcn_s_setprio(1);
#pragma unroll
    for (int nb = 0; nb < 4; nb++) {
      const half8 kf0 = *(const half8*)(Kc + (size_t)(nb * 16 + mm) * 64 + (size_t)(quad ^ sw) * 8);
      const half8 kf1 = *(const half8*)(Kc + (size_t)(nb * 16 + mm) * 64 + (size_t)((4 + quad) ^ sw) * 8);
      s[nb] = __builtin_amdgcn_mfma_f32_16x16x32_f16(aq[0], kf0, f4zero(), 0, 0, 0);
      s[nb] = __builtin_amdgcn_mfma_f32_16x16x32_f16(aq[1], kf1, s[nb], 0, 0, 0);
    }
    __builtin_amdgcn_s_setprio(0);

    // (4) packed-f16 softmax + P write (b64, XOR-swizzled, permuted-k layout)
    const half2v mk01 = cvtpk(mkc[0], mkc[1]);
    const half2v mk23 = cvtpk(mkc[2], mkc[3]);
#pragma unroll
    for (int r = 0; r < 4; r++) {
      half2v pb01, pb23, iv01, iv23;
      if (TILED >= 1) {
        pb01 = *(const half2v*)&pbc[r].x;
        pb23 = *(const half2v*)&pbc[r].z;
      } else {
        float pv[4];
#pragma unroll
        for (int nb = 0; nb < 4; nb++)
          pv[nb] = pb32[((size_t)h_ * 2048 + q0 + quad * 4 + r) * 2048 + k0 + nb * 16 + mm] * L2E;
        pb01 = cvtpk(pv[0], pv[1]); pb23 = cvtpk(pv[2], pv[3]);
      }
      if (TILED == 2) {
        iv01 = *(const half2v*)&invc[r].x;
        iv23 = *(const half2v*)&invc[r].z;
      } else {
        float ivv[4];
#pragma unroll
        for (int nb = 0; nb < 4; nb++) {
          const float u = fmaxf(tqf[r] - tkc[nb], 0.f);
          ivv[nb] = fmaf(u, L2E, 86561.70245333781f) *
                    __builtin_amdgcn_rcpf(fmaf(u, 9.f, 480000.f));
        }
        iv01 = cvtpk(ivv[0], ivv[1]); iv23 = cvtpk(ivv[2], ivv[3]);
      }
      const half2v s01 = cvtpk(s[0][r], s[1][r]);
      const half2v s23 = cvtpk(s[2][r], s[3][r]);
      const half2v t01 = __builtin_elementwise_fma(s01, iv01, pb01 + mk01);
      const half2v t23 = __builtin_elementwise_fma(s23, iv23, pb23 + mk23);
      half2v p01, p23;
      p01.x = hexp2_(t01.x); p01.y = hexp2_(t01.y);
      p23.x = hexp2_(t23.x); p23.y = hexp2_(t23.y);
      l_r[r] = fdot2f(p01, l_r[r]);
      l_r[r] = fdot2f(p23, l_r[r]);
      const int prow = quad * 4 + r;
      union { half2v h2[2]; half4v h4; } uu;
      uu.h2[0] = p01; uu.h2[1] = p23;
      *(half4v*)((char*)P[w] + prow * 128 + ((mm * 8) ^ ((prow & 7) << 4))) = uu.h4;
    }

    // (5) PV from LDS (A = P in permuted-k storage, B = V with matching k order)
    const u16* Vc = Vls[cur];
    const char* Pb = (const char*)P[w] + mm * 128;
    const int pxor = (mm & 7) << 4;
    const half8 ap0 = *(const half8*)(Pb + ((quad * 16) ^ pxor));
    const half8 ap1 = *(const half8*)(Pb + ((64 + quad * 16) ^ pxor));
    __builtin_amdgcn_s_setprio(1);
#pragma unroll
    for (int ob = 0; ob < 4; ob++) {
      const half8 vf0 = *(const half8*)(Vc + (size_t)(ob * 16 + mm) * 64 + (size_t)(quad ^ sw) * 8);
      const half8 vf1 = *(const half8*)(Vc + (size_t)(ob * 16 + mm) * 64 + (size_t)((4 + quad) ^ sw) * 8);
      o[ob] = __builtin_amdgcn_mfma_f32_16x16x32_f16(ap0, vf0, o[ob], 0, 0, 0);
      o[ob] = __builtin_amdgcn_mfma_f32_16x16x32_f16(ap1, vf1, o[ob], 0, 0, 0);
    }
    __builtin_amdgcn_s_setprio(0);

    // (6) rotate prefetched operands (waits vmcnt(2): staging stays in flight)
#pragma unroll
    for (int r = 0; r < 4; r++) { pbc[r] = pbn[r]; invc[r] = invn[r]; }
#pragma unroll
    for (int nb = 0; nb < 4; nb++) { tkc[nb] = tkn[nb]; mkc[nb] = mkn[nb]; }
    cur ^= 1;
  }

#pragma unroll
  for (int r = 0; r < 4; r++) {
    float l = l_r[r];
#pragma unroll
    for (int sh = 1; sh < 16; sh <<= 1) l += __shfl_xor(l, sh, 64);  // sum over mm within quad-group
    const float rl = __builtin_amdgcn_rcpf(l);
    const int qrow = q0 + quad * 4 + r;
#pragma unroll
    for (int ob = 0; ob < 4; ob++)
      ctx[((size_t)b_ * 2048 + qrow) * 512 + h_ * 64 + ob * 16 + mm] = f2h(o[ob][r] * rl);
  }
}

// ---------------------------------------------------------------------------
// LayerNorm over H=512: 1 wave/row, 4 rows/block. f16 out always, f32 optional.
// ---------------------------------------------------------------------------
__global__ __launch_bounds__(256) void ln_kernel(
    const float* __restrict__ in, const float* __restrict__ g, const float* __restrict__ bb,
    float* __restrict__ of, u16* __restrict__ obf) {
  const int lane = threadIdx.x & 63, w = threadIdx.x >> 6;
  const int row = blockIdx.x * 4 + w;
  const float* x = in + (size_t)row * 512;
  float v[8];
  const float4 t0 = *(const float4*)(x + lane * 8);
  const float4 t1 = *(const float4*)(x + lane * 8 + 4);
  v[0] = t0.x; v[1] = t0.y; v[2] = t0.z; v[3] = t0.w;
  v[4] = t1.x; v[5] = t1.y; v[6] = t1.z; v[7] = t1.w;
  float s = 0.f;
#pragma unroll
  for (int i = 0; i < 8; i++) s += v[i];
#pragma unroll
  for (int sh = 1; sh < 64; sh <<= 1) s += __shfl_xor(s, sh, 64);
  const float mean = s * (1.0f / 512.0f);
  float sq = 0.f;
#pragma unroll
  for (int i = 0; i < 8; i++) { const float d = v[i] - mean; sq += d * d; }
#pragma unroll
  for (int sh = 1; sh < 64; sh <<= 1) sq += __shfl_xor(sq, sh, 64);
  const float rstd = rsqrtf(sq * (1.0f / 512.0f) + 1e-12f);
#pragma unroll
  for (int i = 0; i < 8; i++) {
    const int col = lane * 8 + i;
    const float y = (v[i] - mean) * rstd * g[col] + bb[col];
    if (of) of[(size_t)row * 512 + col] = y;
    obf[(size_t)row * 512 + col] = f2h(y);
  }
}

// ---------------------------------------------------------------------------
extern "C" void kernel_launch(void* const* d_in, const int* in_sizes, int n_in,
                              void* d_out, int out_size, void* d_ws, size_t ws_size,
                              hipStream_t stream) {
  const float* x_in = (const float*)d_in[0];
  const float* mask = (const float*)d_in[1];
  const float* pb   = (const float*)d_in[2];
  const int*   ts   = (const int*)d_in[3];
  const float* wq = (const float*)d_in[4];  const float* bq = (const float*)d_in[5];
  const float* wk = (const float*)d_in[6];  const float* bk = (const float*)d_in[7];
  const float* wvp = (const float*)d_in[8]; const float* bv = (const float*)d_in[9];
  const float* wo = (const float*)d_in[10]; const float* bo = (const float*)d_in[11];
  const float* ln1g = (const float*)d_in[12]; const float* ln1b = (const float*)d_in[13];
  const float* wi = (const float*)d_in[14]; const float* bi = (const float*)d_in[15];
  const float* wo2 = (const float*)d_in[16]; const float* bo2 = (const float*)d_in[17];
  const float* ln2g = (const float*)d_in[18]; const float* ln2b = (const float*)d_in[19];

  char* ws = (char*)d_ws;
  const size_t o_wqkv  = 0;
  const size_t o_woT   = 6291456;
  const size_t o_wiT   = 8388608;
  const size_t o_wo2T  = 16777216;
  const size_t o_maskE = 25165824;
  const size_t o_tsf   = 25198592;
  const size_t o_xbf   = 25231360;
  const size_t o_qb    = 33619968;
  const size_t o_kb    = 42008576;
  const size_t o_vb    = 50397184;
  const size_t o_ctx   = 58785792;
  const size_t o_attnb = 67174400;
  const size_t o_tmp   = 75563008;
  const size_t o_pbT   = 92340224;    // 67,108,864 B
  const size_t o_invT  = 159449088;   // 33,554,432 B
  const int tiled = (ws_size >= o_invT + 33554432ull) ? 2
                  : (ws_size >= o_pbT + 67108864ull) ? 1 : 0;

  u16*   wqkvT = (u16*)(ws + o_wqkv);
  u16*   woT   = (u16*)(ws + o_woT);
  u16*   wiT   = (u16*)(ws + o_wiT);
  u16*   wo2T  = (u16*)(ws + o_wo2T);
  float* maskE = (float*)(ws + o_maskE);
  float* tsf   = (float*)(ws + o_tsf);
  u16*   xbf   = (u16*)(ws + o_xbf);
  u16*   qb    = (u16*)(ws + o_qb);
  u16*   kb    = (u16*)(ws + o_kb);
  u16*   vb    = (u16*)(ws + o_vb);
  u16*   ctx   = (u16*)(ws + o_ctx);
  u16*   hb    = (u16*)(ws + o_qb);
  u16*   attnb = (u16*)(ws + o_attnb);
  float* tmp   = (float*)(ws + o_tmp);
  u16*   pbT   = (u16*)(ws + o_pbT);
  u16*   invT  = (u16*)(ws + o_invT);

  const dim3 blk(256);
  const dim3 blk512(512);
  transpose_cast_kernel<<<dim3(16, 16, 4), blk, 0, stream>>>(wq,  wqkvT,          512, 512, 786432);
  transpose_cast_kernel<<<dim3(16, 16, 4), blk, 0, stream>>>(wk,  wqkvT + 262144, 512, 512, 786432);
  transpose_cast_kernel<<<dim3(16, 16, 4), blk, 0, stream>>>(wvp, wqkvT + 524288, 512, 512, 786432);
  transpose_cast_kernel<<<dim3(16, 16, 4), blk, 0, stream>>>(wo,  woT,  512, 512,  262144);
  transpose_cast_kernel<<<dim3(64, 16, 4), blk, 0, stream>>>(wi,  wiT,  512, 2048, 1048576);
  transpose_cast_kernel<<<dim3(16, 64, 4), blk, 0, stream>>>(wo2, wo2T, 2048, 512, 1048576);
  maskts_kernel<<<32, blk, 0, stream>>>(mask, ts, maskE, tsf);
  cast_kernel<<<4096, blk, 0, stream>>>(x_in, xbf);
  if (tiled >= 1) pb_tile_kernel<<<32768, blk, 0, stream>>>(pb, pbT);
  if (tiled == 2) inv_tile_kernel<<<16384, blk, 0, stream>>>(ts, invT);

  for (int l = 0; l < 4; l++) {
    gemm8_kernel<1536, 512, 4><<<dim3(32, 12), blk512, 0, stream>>>(
        xbf, wqkvT + (size_t)l * 786432, bq + l * 512, bk + l * 512, bv + l * 512,
        qb, kb, vb);
    if (tiled == 2)
      flash4_kernel<2><<<dim3(16, 32), blk512, 0, stream>>>(qb, kb, vb, pbT, invT, pb, maskE, tsf, ctx);
    else if (tiled == 1)
      flash4_kernel<1><<<dim3(16, 32), blk512, 0, stream>>>(qb, kb, vb, pbT, nullptr, pb, maskE, tsf, ctx);
    else
      flash4_kernel<0><<<dim3(16, 32), blk512, 0, stream>>>(qb, kb, vb, nullptr, nullptr, pb, maskE, tsf, ctx);
    gemm_kernel<128, 64, 512, 512, 2><<<dim3(64, 8), blk, 0, stream>>>(
        ctx, woT + (size_t)l * 262144, bo + l * 512, nullptr, nullptr, xbf,
        tmp, nullptr, nullptr);
    ln_kernel<<<2048, blk, 0, stream>>>(tmp, ln1g + l * 512, ln1b + l * 512, nullptr, attnb);
    gemm8_kernel<2048, 512, 3><<<dim3(32, 16), blk512, 0, stream>>>(
        attnb, wiT + (size_t)l * 1048576, bi + l * 2048, nullptr, nullptr,
        hb, nullptr, nullptr);
    gemm_kernel<128, 64, 512, 2048, 2><<<dim3(64, 8), blk, 0, stream>>>(
        hb, wo2T + (size_t)l * 1048576, bo2 + l * 512, nullptr, nullptr, attnb,
        tmp, nullptr, nullptr);
    ln_kernel<<<2048, blk, 0, stream>>>(tmp, ln2g + l * 512, ln2b + l * 512,
                                        (l == 3) ? (float*)d_out : nullptr, xbf);
  }
  (void)in_sizes; (void)n_in; (void)out_size;
}